// Round 5
// baseline (463.559 us; speedup 1.0000x reference)
//
#include <hip/hip_runtime.h>

typedef __bf16 bf16x8 __attribute__((ext_vector_type(8)));
typedef float f32x4 __attribute__((ext_vector_type(4)));

static constexpr int TOKS = 43520;   // B * LQ
static constexpr int LQN  = 21760;

__device__ __forceinline__ unsigned short f2bf(float f) {
  union { float f; unsigned u; } v; v.f = f;
  return (unsigned short)((v.u + 0x7fffu + ((v.u >> 16) & 1u)) >> 16);
}
__device__ __forceinline__ float bf2f(unsigned short b) {
  union { unsigned u; float f; } v; v.u = ((unsigned)b) << 16; return v.f;
}

// ---- fused prep + weight transpose + bias concat (one launch)
__global__ __launch_bounds__(256) void prewt_kernel(
    const float* __restrict__ src, const float* __restrict__ pos,
    unsigned short* __restrict__ srcb, unsigned short* __restrict__ qb,
    const float* __restrict__ W_val, const float* __restrict__ W_off,
    const float* __restrict__ W_attn, const float* __restrict__ W_out,
    const float* __restrict__ W1, const float* __restrict__ W2,
    const float* __restrict__ b_off, const float* __restrict__ b_attn,
    unsigned short* __restrict__ Wt_val, unsigned short* __restrict__ Wt_oa,
    unsigned short* __restrict__ Wt_out,
    unsigned short* __restrict__ Wt_1, unsigned short* __restrict__ Wt_2,
    float* __restrict__ b_oa) {
  const int bid = blockIdx.x;
  if (bid < 10880) {
    int i = bid * 256 + threadIdx.x;
    float4 s = ((const float4*)src)[i], p = ((const float4*)pos)[i];
    ((ushort4*)srcb)[i] = make_ushort4(f2bf(s.x), f2bf(s.y), f2bf(s.z), f2bf(s.w));
    ((ushort4*)qb)[i]   = make_ushort4(f2bf(s.x + p.x), f2bf(s.y + p.y),
                                       f2bf(s.z + p.z), f2bf(s.w + p.w));
    return;
  }
  int gid = (bid - 10880) * 256 + threadIdx.x;
  if (gid >= 754048) return;
  if (gid >= 753664) {
    int i = gid - 753664;
    b_oa[i] = (i < 256) ? b_off[i] : b_attn[i - 256];
    return;
  }
  const float* W; unsigned short* Wt; int idx, K, nsh;
  if (gid < 65536)       { W = W_val;  Wt = Wt_val;          idx = gid;          K = 256;  nsh = 8;  }
  else if (gid < 131072) { W = W_off;  Wt = Wt_oa;           idx = gid - 65536;  K = 256;  nsh = 8;  }
  else if (gid < 163840) { W = W_attn; Wt = Wt_oa + 65536;   idx = gid - 131072; K = 256;  nsh = 7;  }
  else if (gid < 229376) { W = W_out;  Wt = Wt_out;          idx = gid - 163840; K = 256;  nsh = 8;  }
  else if (gid < 491520) { W = W1;     Wt = Wt_1;            idx = gid - 229376; K = 256;  nsh = 10; }
  else                   { W = W2;     Wt = Wt_2;            idx = gid - 491520; K = 1024; nsh = 8;  }
  int k = idx >> nsh, n = idx & ((1 << nsh) - 1);
  Wt[n * K + k] = f2bf(W[idx]);
}

// ---- 128x128 GEMM body: R2 K-loop verbatim. Epilogue computes R2's exact values,
// stages FINAL bf16 into LDS (full tile, pitch 136 shorts), re-reads row-contiguous,
// stores wide uint4 (kills 2B-scatter write amplification).
template <int K>
__device__ __forceinline__ void gemm_body(unsigned short* __restrict__ lds,
                                          const unsigned short* __restrict__ A,
                                          const unsigned short* __restrict__ Bt,
                                          const float* __restrict__ bias,
                                          unsigned short* __restrict__ Cp,
                                          int N, int bm, int bn) {
  unsigned short* As = lds;             // 2*5120 shorts
  unsigned short* Bs = lds + 2 * 5120;  // 2*5120 shorts
  const int t = threadIdx.x;
  const int wave = t >> 6, lane = t & 63;
  const int wm = (wave & 1) << 6, wn = (wave >> 1) << 6;
  const int lr = lane & 15, lq = lane >> 4;
  const int row0 = t >> 2, cb0 = (t & 3) << 3;
  f32x4 acc[4][4] = {};
  const unsigned short* ga = A  + (size_t)(bm * 128 + row0) * K + cb0;
  const unsigned short* gb = Bt + (size_t)(bn * 128 + row0) * K + cb0;
  const size_t gs = (size_t)64 * K;
  uint4 pa0 = *(const uint4*)ga;
  uint4 pa1 = *(const uint4*)(ga + gs);
  uint4 pb0 = *(const uint4*)gb;
  uint4 pb1 = *(const uint4*)(gb + gs);
  int p = 0;
#pragma unroll 1
  for (int k0 = 0; k0 < K; k0 += 32) {
    unsigned short* Ab = As + p * 5120;
    unsigned short* Bb = Bs + p * 5120;
    *(uint4*)&Ab[row0 * 40 + cb0] = pa0;
    *(uint4*)&Ab[(row0 + 64) * 40 + cb0] = pa1;
    *(uint4*)&Bb[row0 * 40 + cb0] = pb0;
    *(uint4*)&Bb[(row0 + 64) * 40 + cb0] = pb1;
    __syncthreads();
    if (k0 + 32 < K) {
      pa0 = *(const uint4*)(ga + k0 + 32);
      pa1 = *(const uint4*)(ga + gs + k0 + 32);
      pb0 = *(const uint4*)(gb + k0 + 32);
      pb1 = *(const uint4*)(gb + gs + k0 + 32);
    }
    bf16x8 af[4], bfr[4];
#pragma unroll
    for (int i = 0; i < 4; i++) af[i] = *(const bf16x8*)&Ab[(wm + i * 16 + lr) * 40 + lq * 8];
#pragma unroll
    for (int j = 0; j < 4; j++) bfr[j] = *(const bf16x8*)&Bb[(wn + j * 16 + lr) * 40 + lq * 8];
#pragma unroll
    for (int i = 0; i < 4; i++)
#pragma unroll
      for (int j = 0; j < 4; j++)
        acc[i][j] = __builtin_amdgcn_mfma_f32_16x16x32_bf16(af[i], bfr[j], acc[i][j], 0, 0, 0);
    p ^= 1;
  }
  // ---- store-transpose epilogue: values identical to R2's C-write (f2bf(acc+bv))
  unsigned short* st = lds;              // 128*136*2 = 34816B <= 40960B
  __syncthreads();                       // K-loop LDS reads done
#pragma unroll
  for (int j = 0; j < 4; j++) {
    const int cc = wn + j * 16 + lr;
    const float bv = bias[bn * 128 + cc];
#pragma unroll
    for (int i = 0; i < 4; i++)
#pragma unroll
      for (int r = 0; r < 4; r++)
        st[(wm + i * 16 + lq * 4 + r) * 136 + cc] = f2bf(acc[i][j][r] + bv);
  }
  __syncthreads();
  const int rr = t >> 1;                 // 0..127
  const int c0 = (t & 1) * 64;           // 0 / 64
  unsigned short* dst = Cp + (size_t)(bm * 128 + rr) * N + bn * 128 + c0;
  const unsigned short* sp = st + rr * 136 + c0;
#pragma unroll
  for (int q = 0; q < 8; q++)
    ((uint4*)dst)[q] = *(const uint4*)(sp + q * 8);
}

__global__ __launch_bounds__(256) void proj_kernel(
    const unsigned short* __restrict__ srcb, const unsigned short* __restrict__ qb,
    const unsigned short* __restrict__ Wt_val, const unsigned short* __restrict__ Wt_oa,
    const float* __restrict__ b_val, const float* __restrict__ b_oa,
    unsigned short* __restrict__ valb, unsigned short* __restrict__ oab) {
  __shared__ unsigned short lds[4 * 5120];
  const int bn = blockIdx.y;
  if (bn < 2)
    gemm_body<256>(lds, srcb, Wt_val, b_val, valb, 256, blockIdx.x, bn);
  else
    gemm_body<256>(lds, qb, Wt_oa, b_oa, oab, 384, blockIdx.x, bn - 2);
}

// ---- BN=256 GEMM body: R2 K-loop + R2's PROVEN LN computation verbatim.
// Only the final store goes through an LDS transpose (per 16-row slice) to emit
// wide uint4/float4 stores instead of 2B scatter.
// MODE 0: relu -> bf16 (ffn1).  MODE 1: +res, LN -> bf16 (out+LN1).
// MODE 2: +res, LN -> f32 (ffn2+LN2).
template <int K, int MODE>
__device__ __forceinline__ void big_body(unsigned short* __restrict__ lds,
                                         const unsigned short* __restrict__ A,
                                         const unsigned short* __restrict__ Bt,
                                         const float* __restrict__ bias,
                                         const unsigned short* __restrict__ res,
                                         const float* __restrict__ gamma,
                                         const float* __restrict__ beta,
                                         void* __restrict__ outp,
                                         int N, int bm, int bn) {
  unsigned short* As = lds;              // 2*5120 shorts
  unsigned short* Bs = lds + 2 * 5120;   // 2*10240 shorts
  const int t = threadIdx.x;
  const int wave = t >> 6, lane = t & 63;
  const int wm = (wave & 1) << 6, wn = (wave >> 1) << 7;   // wn in {0,128}
  const int lr = lane & 15, lq = lane >> 4;
  const int row0 = t >> 2, cb0 = (t & 3) << 3;
  f32x4 acc[4][8] = {};
  const unsigned short* ga = A  + (size_t)(bm * 128 + row0) * K + cb0;
  const unsigned short* gb = Bt + (size_t)(bn * 256 + row0) * K + cb0;
  const size_t gs = (size_t)64 * K;
  uint4 pa0 = *(const uint4*)ga;
  uint4 pa1 = *(const uint4*)(ga + gs);
  uint4 pb0 = *(const uint4*)gb;
  uint4 pb1 = *(const uint4*)(gb + gs);
  uint4 pb2 = *(const uint4*)(gb + 2 * gs);
  uint4 pb3 = *(const uint4*)(gb + 3 * gs);
  int p = 0;
#pragma unroll 1
  for (int k0 = 0; k0 < K; k0 += 32) {
    unsigned short* Ab = As + p * 5120;
    unsigned short* Bb = Bs + p * 10240;
    *(uint4*)&Ab[row0 * 40 + cb0] = pa0;
    *(uint4*)&Ab[(row0 + 64) * 40 + cb0] = pa1;
    *(uint4*)&Bb[row0 * 40 + cb0] = pb0;
    *(uint4*)&Bb[(row0 + 64) * 40 + cb0] = pb1;
    *(uint4*)&Bb[(row0 + 128) * 40 + cb0] = pb2;
    *(uint4*)&Bb[(row0 + 192) * 40 + cb0] = pb3;
    __syncthreads();
    if (k0 + 32 < K) {
      pa0 = *(const uint4*)(ga + k0 + 32);
      pa1 = *(const uint4*)(ga + gs + k0 + 32);
      pb0 = *(const uint4*)(gb + k0 + 32);
      pb1 = *(const uint4*)(gb + gs + k0 + 32);
      pb2 = *(const uint4*)(gb + 2 * gs + k0 + 32);
      pb3 = *(const uint4*)(gb + 3 * gs + k0 + 32);
    }
    bf16x8 af[4], bfr[8];
#pragma unroll
    for (int i = 0; i < 4; i++) af[i]  = *(const bf16x8*)&Ab[(wm + i * 16 + lr) * 40 + lq * 8];
#pragma unroll
    for (int j = 0; j < 8; j++) bfr[j] = *(const bf16x8*)&Bb[(wn + j * 16 + lr) * 40 + lq * 8];
#pragma unroll
    for (int i = 0; i < 4; i++)
#pragma unroll
      for (int j = 0; j < 8; j++)
        acc[i][j] = __builtin_amdgcn_mfma_f32_16x16x32_bf16(af[i], bfr[j], acc[i][j], 0, 0, 0);
    p ^= 1;
  }
  const int rb = bm * 128 + wm + lq * 4;

  if (MODE == 0) {
    // relu epilogue: stage final bf16 per 16-row slice, wide-store
    unsigned short* st = lds;            // 32*264*2 = 16896B
#pragma unroll
    for (int i = 0; i < 4; i++) {
      __syncthreads();
#pragma unroll
      for (int j = 0; j < 8; j++) {
        const int cc = wn + j * 16 + lr;
        const float bv = bias[bn * 256 + cc];
#pragma unroll
        for (int r = 0; r < 4; r++)
          st[(((wave & 1) << 4) + lq * 4 + r) * 264 + cc] = f2bf(fmaxf(acc[i][j][r] + bv, 0.f));
      }
      __syncthreads();
      const int rr = t >> 3;                 // 0..31
      const int c0 = (t & 7) * 32;           // 0..224
      const int grow = bm * 128 + (rr < 16 ? i * 16 + rr : 64 + i * 16 + (rr - 16));
      unsigned short* dst = (unsigned short*)outp + (size_t)grow * N + bn * 256 + c0;
      const unsigned short* sp = st + rr * 264 + c0;
#pragma unroll
      for (int q = 0; q < 4; q++)
        ((uint4*)dst)[q] = *(const uint4*)(sp + q * 8);
    }
    return;
  }

  // ---- fused LayerNorm (R2-proven computation, verbatim)
  __syncthreads();                       // LDS about to be reused for reduction
  float* red = (float*)lds;              // [sum|sq][wnIdx][128 rows] = 512 floats
  const int wnIdx = wave >> 1;
  float vsum[4][4], vsq[4][4];
#pragma unroll
  for (int i = 0; i < 4; i++)
#pragma unroll
    for (int r = 0; r < 4; r++) { vsum[i][r] = 0.f; vsq[i][r] = 0.f; }
#pragma unroll
  for (int j = 0; j < 8; j++) {
    const int col = wn + j * 16 + lr;
    const float bv = bias[col];
#pragma unroll
    for (int i = 0; i < 4; i++)
#pragma unroll
      for (int r = 0; r < 4; r++) {
        const int grow = rb + i * 16 + r;
        float v = acc[i][j][r] + bv + bf2f(res[(size_t)grow * 256 + col]);
        acc[i][j][r] = v;
        vsum[i][r] += v;
        vsq[i][r]  += v * v;
      }
  }
#pragma unroll
  for (int m = 1; m <= 8; m <<= 1)
#pragma unroll
    for (int i = 0; i < 4; i++)
#pragma unroll
      for (int r = 0; r < 4; r++) {
        vsum[i][r] += __shfl_xor(vsum[i][r], m, 64);
        vsq[i][r]  += __shfl_xor(vsq[i][r],  m, 64);
      }
  if (lr == 0) {
#pragma unroll
    for (int i = 0; i < 4; i++)
#pragma unroll
      for (int r = 0; r < 4; r++) {
        const int lrow = wm + i * 16 + lq * 4 + r;
        red[wnIdx * 128 + lrow]       = vsum[i][r];
        red[256 + wnIdx * 128 + lrow] = vsq[i][r];
      }
  }
  __syncthreads();
  float mu[4][4], rstd[4][4];
#pragma unroll
  for (int i = 0; i < 4; i++)
#pragma unroll
    for (int r = 0; r < 4; r++) {
      const int lrow = wm + i * 16 + lq * 4 + r;
      const float ts = vsum[i][r] + red[(1 - wnIdx) * 128 + lrow];
      const float tq = vsq[i][r]  + red[256 + (1 - wnIdx) * 128 + lrow];
      const float m_ = ts * (1.f / 256.f);
      float var = tq * (1.f / 256.f) - m_ * m_;
      mu[i][r] = m_;
      rstd[i][r] = rsqrtf(var + 1e-5f);
    }
  float g8[8], b8[8];
#pragma unroll
  for (int j = 0; j < 8; j++) {
    g8[j] = gamma[wn + j * 16 + lr];
    b8[j] = beta[wn + j * 16 + lr];
  }
  // ---- store via LDS transpose, per 16-row slice; y identical to R2's formula
  const int rsl = ((wave & 1) << 4) + lq * 4;
  const int rr = t >> 3;                 // 0..31
  const int c0 = (t & 7) * 32;           // 0..224
#pragma unroll
  for (int i = 0; i < 4; i++) {
    __syncthreads();                     // prior reads (red / previous slice) done
    if (MODE == 1) {
      unsigned short* st = lds;          // 32*264*2 = 16896B
#pragma unroll
      for (int j = 0; j < 8; j++) {
        const int cc = wn + j * 16 + lr;
#pragma unroll
        for (int r = 0; r < 4; r++) {
          const float y = (acc[i][j][r] - mu[i][r]) * rstd[i][r] * g8[j] + b8[j];
          st[(rsl + r) * 264 + cc] = f2bf(y);
        }
      }
      __syncthreads();
      const int grow = bm * 128 + (rr < 16 ? i * 16 + rr : 64 + i * 16 + (rr - 16));
      unsigned short* dst = (unsigned short*)outp + (size_t)grow * 256 + c0;
      const unsigned short* sp = lds + rr * 264 + c0;
#pragma unroll
      for (int q = 0; q < 4; q++)
        ((uint4*)dst)[q] = *(const uint4*)(sp + q * 8);
    } else {
      float* st = (float*)lds;           // 32*260*4 = 33280B <= 61440B
#pragma unroll
      for (int j = 0; j < 8; j++) {
        const int cc = wn + j * 16 + lr;
#pragma unroll
        for (int r = 0; r < 4; r++) {
          const float y = (acc[i][j][r] - mu[i][r]) * rstd[i][r] * g8[j] + b8[j];
          st[(rsl + r) * 260 + cc] = y;
        }
      }
      __syncthreads();
      const int grow = bm * 128 + (rr < 16 ? i * 16 + rr : 64 + i * 16 + (rr - 16));
      float* dst = (float*)outp + (size_t)grow * 256 + c0;
      const float* sp = (const float*)lds + rr * 260 + c0;
#pragma unroll
      for (int q = 0; q < 8; q++)
        ((float4*)dst)[q] = *(const float4*)(sp + q * 4);
    }
  }
}

__global__ __launch_bounds__(256, 2) void out_ln_kernel(
    const unsigned short* __restrict__ A, const unsigned short* __restrict__ Bt,
    const float* __restrict__ bias, const unsigned short* __restrict__ res,
    const float* __restrict__ gamma, const float* __restrict__ beta,
    unsigned short* __restrict__ C) {
  __shared__ unsigned short lds[2 * 5120 + 2 * 10240];
  big_body<256, 1>(lds, A, Bt, bias, res, gamma, beta, C, 256, blockIdx.x, 0);
}

__global__ __launch_bounds__(256, 2) void ffn1_kernel(
    const unsigned short* __restrict__ A, const unsigned short* __restrict__ Bt,
    const float* __restrict__ bias, unsigned short* __restrict__ C) {
  __shared__ unsigned short lds[2 * 5120 + 2 * 10240];
  big_body<256, 0>(lds, A, Bt, bias, nullptr, nullptr, nullptr, C, 1024,
                   blockIdx.x, blockIdx.y);
}

__global__ __launch_bounds__(256, 2) void ffn2_ln_kernel(
    const unsigned short* __restrict__ A, const unsigned short* __restrict__ Bt,
    const float* __restrict__ bias, const unsigned short* __restrict__ res,
    const float* __restrict__ gamma, const float* __restrict__ beta,
    float* __restrict__ C) {
  __shared__ unsigned short lds[2 * 5120 + 2 * 10240];
  big_body<1024, 2>(lds, A, Bt, bias, res, gamma, beta, C, 256, blockIdx.x, 0);
}

// ---- bf16x8 (uint4) fused unpack+FMA into fp32 acc
__device__ __forceinline__ void fma8(uint4 v, float w, float* a) {
  const unsigned uu[4] = {v.x, v.y, v.z, v.w};
#pragma unroll
  for (int i = 0; i < 4; i++) {
    union { unsigned u; float f; } lo, hi;
    lo.u = uu[i] << 16;
    hi.u = uu[i] & 0xffff0000u;
    a[2 * i]     += w * lo.f;
    a[2 * i + 1] += w * hi.f;
  }
}

// ---- deformable attention (R0 exact): two-phase, int4 byte-offset tables
__global__ __launch_bounds__(256) void deform_kernel(const unsigned short* __restrict__ valb,
                                                     const unsigned short* __restrict__ oab,
                                                     const float* __restrict__ refp,
                                                     unsigned short* __restrict__ outb) {
  __shared__ float4 sW[8][8][17];   // 4 corner weights (x attn)
  __shared__ int4   sI[8][8][17];   // 4 corner BYTE offsets (idx*512)
  const int t = threadIdx.x;
  const int bid = blockIdx.x;                     // 5440 blocks
  const int nb = (bid & 7) * 680 + (bid >> 3);    // XCD-contiguous slices
  const int tok0 = nb * 8;

  {
    const int g = t >> 5, h = (t >> 2) & 7, l = t & 3;
    const int tok = tok0 + g;
    const unsigned short* lg = oab + (size_t)tok * 384 + 256 + h * 16;
    uint4 lv0 = ((const uint4*)lg)[0];
    uint4 lv1 = ((const uint4*)lg)[1];
    const unsigned lw[8] = {lv0.x, lv0.y, lv0.z, lv0.w, lv1.x, lv1.y, lv1.z, lv1.w};
    float w[16];
#pragma unroll
    for (int i = 0; i < 8; i++) {
      union { unsigned u; float f; } lo, hi;
      lo.u = lw[i] << 16; hi.u = lw[i] & 0xffff0000u;
      w[2 * i] = lo.f; w[2 * i + 1] = hi.f;
    }
    float mx = -1e30f;
#pragma unroll
    for (int i = 0; i < 16; i++) mx = fmaxf(mx, w[i]);
    float s = 0.f;
#pragma unroll
    for (int i = 0; i < 16; i++) { w[i] = __expf(w[i] - mx); s += w[i]; }
    const float inv = 1.f / s;
    uint4 ov = *(const uint4*)(oab + (size_t)tok * 384 + h * 32 + l * 8);
    const unsigned owv[4] = {ov.x, ov.y, ov.z, ov.w};
    float off[8];
#pragma unroll
    for (int i = 0; i < 4; i++) {
      union { unsigned u; float f; } lo, hi;
      lo.u = owv[i] << 16; hi.u = owv[i] & 0xffff0000u;
      off[2 * i] = lo.f; off[2 * i + 1] = hi.f;
    }
    const float* rp = refp + (size_t)tok * 8 + l * 2;
    const int S = 128 >> l;
    const float Sf = (float)S;
    const float rx = rp[0] * Sf - 0.5f;
    const float ry = rp[1] * Sf - 0.5f;
#pragma unroll
    for (int p = 0; p < 4; p++) {
      const int idx = l * 4 + p;
      const float x = rx + off[p * 2 + 0];
      const float y = ry + off[p * 2 + 1];
      const float aw = w[idx] * inv;
      const float x0f = floorf(x), y0f = floorf(y);
      const int x0 = (int)x0f, y0 = (int)y0f;
      const float fx = x - x0f, fy = y - y0f;
      const bool xin0 = (x0 >= 0) & (x0 < S), xin1 = (x0 + 1 >= 0) & (x0 + 1 < S);
      const bool yin0 = (y0 >= 0) & (y0 < S), yin1 = (y0 + 1 >= 0) & (y0 + 1 < S);
      const int xc0 = min(max(x0, 0), S - 1), xc1 = min(max(x0 + 1, 0), S - 1);
      const int yc0 = min(max(y0, 0), S - 1), yc1 = min(max(y0 + 1, 0), S - 1);
      sW[g][h][idx] = make_float4(aw * (1.f - fx) * (1.f - fy) * (float)(xin0 & yin0),
                                  aw * fx * (1.f - fy)         * (float)(xin1 & yin0),
                                  aw * (1.f - fx) * fy         * (float)(xin0 & yin1),
                                  aw * fx * fy                 * (float)(xin1 & yin1));
      sI[g][h][idx] = make_int4((yc0 * S + xc0) << 9, (yc0 * S + xc1) << 9,
                                (yc1 * S + xc0) << 9, (yc1 * S + xc1) << 9);
    }
  }
  __syncthreads();

  const int g = t >> 5, h = (t >> 2) & 7, dc = t & 3;
  const int tok = tok0 + g;
  const int b = tok / LQN;
  float acc[8] = {0.f, 0.f, 0.f, 0.f, 0.f, 0.f, 0.f, 0.f};
  const int ST[4] = {0, 16384, 20480, 21504};
#pragma unroll
  for (int l = 0; l < 4; l++) {
    const char* vbc = (const char*)(valb + ((size_t)(b * LQN + ST[l])) * 256 + h * 32 + dc * 8);
#pragma unroll
    for (int p = 0; p < 4; p++) {
      float4 W4 = sW[g][h][l * 4 + p];
      int4   I4 = sI[g][h][l * 4 + p];
      uint4 v00 = *(const uint4*)(vbc + I4.x);
      uint4 v10 = *(const uint4*)(vbc + I4.y);
      uint4 v01 = *(const uint4*)(vbc + I4.z);
      uint4 v11 = *(const uint4*)(vbc + I4.w);
      fma8(v00, W4.x, acc);
      fma8(v10, W4.y, acc);
      fma8(v01, W4.z, acc);
      fma8(v11, W4.w, acc);
    }
  }
  unsigned o[4];
#pragma unroll
  for (int i = 0; i < 4; i++)
    o[i] = (unsigned)f2bf(acc[2 * i]) | ((unsigned)f2bf(acc[2 * i + 1]) << 16);
  *(uint4*)(outb + (size_t)tok * 256 + h * 32 + dc * 8) = make_uint4(o[0], o[1], o[2], o[3]);
}

extern "C" void kernel_launch(void* const* d_in, const int* in_sizes, int n_in,
                              void* d_out, int out_size, void* d_ws, size_t ws_size,
                              hipStream_t stream) {
  (void)in_sizes; (void)n_in; (void)out_size; (void)ws_size;
  const float* src    = (const float*)d_in[0];
  const float* pos    = (const float*)d_in[1];
  const float* refp   = (const float*)d_in[2];
  const float* W_off  = (const float*)d_in[3];
  const float* b_off  = (const float*)d_in[4];
  const float* W_attn = (const float*)d_in[5];
  const float* b_attn = (const float*)d_in[6];
  const float* W_val  = (const float*)d_in[7];
  const float* b_val  = (const float*)d_in[8];
  const float* W_out  = (const float*)d_in[9];
  const float* b_out  = (const float*)d_in[10];
  const float* ln1_g  = (const float*)d_in[11];
  const float* ln1_b  = (const float*)d_in[12];
  const float* W1     = (const float*)d_in[13];
  const float* b1     = (const float*)d_in[14];
  const float* W2     = (const float*)d_in[15];
  const float* b2     = (const float*)d_in[16];
  const float* ln2_g  = (const float*)d_in[17];
  const float* ln2_b  = (const float*)d_in[18];

  char* ws = (char*)d_ws;
  unsigned short* Wt_val = (unsigned short*)ws;          // 65536
  unsigned short* Wt_oa  = Wt_val + 65536;               // 98304
  unsigned short* Wt_out = Wt_oa + 98304;                // 65536
  unsigned short* Wt_1   = Wt_out + 65536;               // 262144
  unsigned short* Wt_2   = Wt_1 + 262144;                // 262144
  float*          b_oa   = (float*)(Wt_2 + 262144);      // 384
  const size_t WPOOL = 2u * 1024 * 1024;

  const size_t SZ_bf = (size_t)TOKS * 256 * 2;           // 22.3 MB
  const size_t SZ_oa = (size_t)TOKS * 384 * 2;           // 33.4 MB

  unsigned short* srcb = (unsigned short*)(ws + WPOOL);
  unsigned short* qb   = (unsigned short*)(ws + WPOOL + SZ_bf);
  unsigned short* valb = (unsigned short*)(ws + WPOOL + 2 * SZ_bf);
  unsigned short* oab  = (unsigned short*)(ws + WPOOL + 3 * SZ_bf);
  unsigned short* h_bf = (unsigned short*)(ws + WPOOL + 3 * SZ_bf + SZ_oa);
  unsigned short* hb   = (unsigned short*)(ws + WPOOL + 3 * SZ_bf + SZ_oa + SZ_bf);
  // alias (lifetime-disjoint):
  unsigned short* attnoutb = qb;     // deform out; qb dead after proj

  // 1. prep + weight transposes + bias concat
  prewt_kernel<<<13826, 256, 0, stream>>>(src, pos, srcb, qb,
                                          W_val, W_off, W_attn, W_out, W1, W2, b_off, b_attn,
                                          Wt_val, Wt_oa, Wt_out, Wt_1, Wt_2, b_oa);

  // 2. merged projections: value (N=256) + off/attn (N=384)
  proj_kernel<<<dim3(340, 5), 256, 0, stream>>>(srcb, qb, Wt_val, Wt_oa, b_val, b_oa,
                                                valb, oab);

  // 3. deformable attention (8 tokens/block, XCD-swizzled)
  deform_kernel<<<TOKS / 8, 256, 0, stream>>>(valb, oab, refp, attnoutb);

  // 4. out-proj + residual(src) + LN1 fused -> h_bf (bf16)
  out_ln_kernel<<<340, 256, 0, stream>>>(attnoutb, Wt_out, b_out, srcb, ln1_g, ln1_b, h_bf);

  // 5. FFN1: W1 + relu -> hb (BN=256 tiles)
  ffn1_kernel<<<dim3(340, 4), 256, 0, stream>>>(h_bf, Wt_1, b1, hb);

  // 6. FFN2 + residual(h) + LN2 fused -> d_out (f32)
  ffn2_ln_kernel<<<340, 256, 0, stream>>>(hb, Wt_2, b2, h_bf, ln2_g, ln2_b, (float*)d_out);
}

// Round 6
// 435.580 us; speedup vs baseline: 1.0642x; 1.0642x over previous
//
#include <hip/hip_runtime.h>

typedef __bf16 bf16x8 __attribute__((ext_vector_type(8)));
typedef float f32x4 __attribute__((ext_vector_type(4)));

static constexpr int TOKS = 43520;   // B * LQ
static constexpr int LQN  = 21760;

__device__ __forceinline__ unsigned short f2bf(float f) {
  union { float f; unsigned u; } v; v.f = f;
  return (unsigned short)((v.u + 0x7fffu + ((v.u >> 16) & 1u)) >> 16);
}
__device__ __forceinline__ float bf2f(unsigned short b) {
  union { unsigned u; float f; } v; v.u = ((unsigned)b) << 16; return v.f;
}

// ---- fused prep + weight transpose + bias concat (one launch)
__global__ __launch_bounds__(256) void prewt_kernel(
    const float* __restrict__ src, const float* __restrict__ pos,
    unsigned short* __restrict__ srcb, unsigned short* __restrict__ qb,
    const float* __restrict__ W_val, const float* __restrict__ W_off,
    const float* __restrict__ W_attn, const float* __restrict__ W_out,
    const float* __restrict__ W1, const float* __restrict__ W2,
    const float* __restrict__ b_off, const float* __restrict__ b_attn,
    unsigned short* __restrict__ Wt_val, unsigned short* __restrict__ Wt_oa,
    unsigned short* __restrict__ Wt_out,
    unsigned short* __restrict__ Wt_1, unsigned short* __restrict__ Wt_2,
    float* __restrict__ b_oa) {
  const int bid = blockIdx.x;
  if (bid < 10880) {
    int i = bid * 256 + threadIdx.x;
    float4 s = ((const float4*)src)[i], p = ((const float4*)pos)[i];
    ((ushort4*)srcb)[i] = make_ushort4(f2bf(s.x), f2bf(s.y), f2bf(s.z), f2bf(s.w));
    ((ushort4*)qb)[i]   = make_ushort4(f2bf(s.x + p.x), f2bf(s.y + p.y),
                                       f2bf(s.z + p.z), f2bf(s.w + p.w));
    return;
  }
  int gid = (bid - 10880) * 256 + threadIdx.x;
  if (gid >= 754048) return;
  if (gid >= 753664) {
    int i = gid - 753664;
    b_oa[i] = (i < 256) ? b_off[i] : b_attn[i - 256];
    return;
  }
  const float* W; unsigned short* Wt; int idx, K, nsh;
  if (gid < 65536)       { W = W_val;  Wt = Wt_val;          idx = gid;          K = 256;  nsh = 8;  }
  else if (gid < 131072) { W = W_off;  Wt = Wt_oa;           idx = gid - 65536;  K = 256;  nsh = 8;  }
  else if (gid < 163840) { W = W_attn; Wt = Wt_oa + 65536;   idx = gid - 131072; K = 256;  nsh = 7;  }
  else if (gid < 229376) { W = W_out;  Wt = Wt_out;          idx = gid - 163840; K = 256;  nsh = 8;  }
  else if (gid < 491520) { W = W1;     Wt = Wt_1;            idx = gid - 229376; K = 256;  nsh = 10; }
  else                   { W = W2;     Wt = Wt_2;            idx = gid - 491520; K = 1024; nsh = 8;  }
  int k = idx >> nsh, n = idx & ((1 << nsh) - 1);
  Wt[n * K + k] = f2bf(W[idx]);
}

// ---- R2-proven 128x128 GEMM body: padded LDS, reg staging, ONE barrier per K-iter.
template <int K, int OUTOP>
__device__ __forceinline__ void gemm_body(unsigned short* __restrict__ As,
                                          unsigned short* __restrict__ Bs,
                                          const unsigned short* __restrict__ A,
                                          const unsigned short* __restrict__ Bt,
                                          const float* __restrict__ bias,
                                          const unsigned short* __restrict__ res,
                                          unsigned short* __restrict__ Cp,
                                          int N, int bm, int bn) {
  const int t = threadIdx.x;
  const int wave = t >> 6, lane = t & 63;
  const int wm = (wave & 1) << 6, wn = (wave >> 1) << 6;
  const int lr = lane & 15, lq = lane >> 4;
  const int row0 = t >> 2, cb0 = (t & 3) << 3;
  f32x4 acc[4][4] = {};
  const unsigned short* ga = A  + (size_t)(bm * 128 + row0) * K + cb0;
  const unsigned short* gb = Bt + (size_t)(bn * 128 + row0) * K + cb0;
  const size_t gs = (size_t)64 * K;
  uint4 pa0 = *(const uint4*)ga;
  uint4 pa1 = *(const uint4*)(ga + gs);
  uint4 pb0 = *(const uint4*)gb;
  uint4 pb1 = *(const uint4*)(gb + gs);
  int p = 0;
#pragma unroll 1
  for (int k0 = 0; k0 < K; k0 += 32) {
    unsigned short* Ab = As + p * 5120;
    unsigned short* Bb = Bs + p * 5120;
    *(uint4*)&Ab[row0 * 40 + cb0] = pa0;
    *(uint4*)&Ab[(row0 + 64) * 40 + cb0] = pa1;
    *(uint4*)&Bb[row0 * 40 + cb0] = pb0;
    *(uint4*)&Bb[(row0 + 64) * 40 + cb0] = pb1;
    __syncthreads();
    if (k0 + 32 < K) {
      pa0 = *(const uint4*)(ga + k0 + 32);
      pa1 = *(const uint4*)(ga + gs + k0 + 32);
      pb0 = *(const uint4*)(gb + k0 + 32);
      pb1 = *(const uint4*)(gb + gs + k0 + 32);
    }
    bf16x8 af[4], bfr[4];
#pragma unroll
    for (int i = 0; i < 4; i++) af[i] = *(const bf16x8*)&Ab[(wm + i * 16 + lr) * 40 + lq * 8];
#pragma unroll
    for (int j = 0; j < 4; j++) bfr[j] = *(const bf16x8*)&Bb[(wn + j * 16 + lr) * 40 + lq * 8];
#pragma unroll
    for (int i = 0; i < 4; i++)
#pragma unroll
      for (int j = 0; j < 4; j++)
        acc[i][j] = __builtin_amdgcn_mfma_f32_16x16x32_bf16(af[i], bfr[j], acc[i][j], 0, 0, 0);
    p ^= 1;
  }
  const int rb = bm * 128 + wm + lq * 4;
  const int cbase = bn * 128 + wn + lr;
#pragma unroll
  for (int j = 0; j < 4; j++) {
    const int col = cbase + j * 16;
    const float bv = bias[col];
#pragma unroll
    for (int i = 0; i < 4; i++) {
#pragma unroll
      for (int r = 0; r < 4; r++) {
        float v = acc[i][j][r] + bv;
        size_t o = (size_t)(rb + i * 16 + r) * N + col;
        if (OUTOP == 1) Cp[o] = f2bf(v);
        else if (OUTOP == 2) Cp[o] = f2bf(fmaxf(v, 0.f));
        else Cp[o] = f2bf(v + bf2f(res[o]));
      }
    }
  }
}

__global__ __launch_bounds__(256) void proj_kernel(
    const unsigned short* __restrict__ srcb, const unsigned short* __restrict__ qb,
    const unsigned short* __restrict__ Wt_val, const unsigned short* __restrict__ Wt_oa,
    const float* __restrict__ b_val, const float* __restrict__ b_oa,
    unsigned short* __restrict__ valb, unsigned short* __restrict__ oab) {
  __shared__ unsigned short As[2 * 5120];
  __shared__ unsigned short Bs[2 * 5120];
  const int bn = blockIdx.y;
  if (bn < 2)
    gemm_body<256, 1>(As, Bs, srcb, Wt_val, b_val, nullptr, valb, 256, blockIdx.x, bn);
  else
    gemm_body<256, 1>(As, Bs, qb, Wt_oa, b_oa, nullptr, oab, 384, blockIdx.x, bn - 2);
}

// ---- R2-proven BN=256 GEMM body with fused LayerNorm epilogue (MODE 1 used).
template <int K, int MODE>
__device__ __forceinline__ void big_body(unsigned short* __restrict__ As,
                                         unsigned short* __restrict__ Bs,
                                         const unsigned short* __restrict__ A,
                                         const unsigned short* __restrict__ Bt,
                                         const float* __restrict__ bias,
                                         const unsigned short* __restrict__ res,
                                         const float* __restrict__ gamma,
                                         const float* __restrict__ beta,
                                         void* __restrict__ outp,
                                         int N, int bm, int bn) {
  const int t = threadIdx.x;
  const int wave = t >> 6, lane = t & 63;
  const int wm = (wave & 1) << 6, wn = (wave >> 1) << 7;   // wn in {0,128}
  const int lr = lane & 15, lq = lane >> 4;
  const int row0 = t >> 2, cb0 = (t & 3) << 3;
  f32x4 acc[4][8] = {};
  const unsigned short* ga = A  + (size_t)(bm * 128 + row0) * K + cb0;
  const unsigned short* gb = Bt + (size_t)(bn * 256 + row0) * K + cb0;
  const size_t gs = (size_t)64 * K;
  uint4 pa0 = *(const uint4*)ga;
  uint4 pa1 = *(const uint4*)(ga + gs);
  uint4 pb0 = *(const uint4*)gb;
  uint4 pb1 = *(const uint4*)(gb + gs);
  uint4 pb2 = *(const uint4*)(gb + 2 * gs);
  uint4 pb3 = *(const uint4*)(gb + 3 * gs);
  int p = 0;
#pragma unroll 1
  for (int k0 = 0; k0 < K; k0 += 32) {
    unsigned short* Ab = As + p * 5120;
    unsigned short* Bb = Bs + p * 10240;
    *(uint4*)&Ab[row0 * 40 + cb0] = pa0;
    *(uint4*)&Ab[(row0 + 64) * 40 + cb0] = pa1;
    *(uint4*)&Bb[row0 * 40 + cb0] = pb0;
    *(uint4*)&Bb[(row0 + 64) * 40 + cb0] = pb1;
    *(uint4*)&Bb[(row0 + 128) * 40 + cb0] = pb2;
    *(uint4*)&Bb[(row0 + 192) * 40 + cb0] = pb3;
    __syncthreads();
    if (k0 + 32 < K) {
      pa0 = *(const uint4*)(ga + k0 + 32);
      pa1 = *(const uint4*)(ga + gs + k0 + 32);
      pb0 = *(const uint4*)(gb + k0 + 32);
      pb1 = *(const uint4*)(gb + gs + k0 + 32);
      pb2 = *(const uint4*)(gb + 2 * gs + k0 + 32);
      pb3 = *(const uint4*)(gb + 3 * gs + k0 + 32);
    }
    bf16x8 af[4], bfr[8];
#pragma unroll
    for (int i = 0; i < 4; i++) af[i]  = *(const bf16x8*)&Ab[(wm + i * 16 + lr) * 40 + lq * 8];
#pragma unroll
    for (int j = 0; j < 8; j++) bfr[j] = *(const bf16x8*)&Bb[(wn + j * 16 + lr) * 40 + lq * 8];
#pragma unroll
    for (int i = 0; i < 4; i++)
#pragma unroll
      for (int j = 0; j < 8; j++)
        acc[i][j] = __builtin_amdgcn_mfma_f32_16x16x32_bf16(af[i], bfr[j], acc[i][j], 0, 0, 0);
    p ^= 1;
  }
  const int rb = bm * 128 + wm + lq * 4;
  if (MODE == 0) {
    const int cbase = bn * 256 + wn + lr;
#pragma unroll
    for (int j = 0; j < 8; j++) {
      const int col = cbase + j * 16;
      const float bv = bias[col];
#pragma unroll
      for (int i = 0; i < 4; i++)
#pragma unroll
        for (int r = 0; r < 4; r++) {
          float v = acc[i][j][r] + bv;
          ((unsigned short*)outp)[(size_t)(rb + i * 16 + r) * N + col] = f2bf(fmaxf(v, 0.f));
        }
    }
    return;
  }
  __syncthreads();
  float* red = (float*)As;
  const int wnIdx = wave >> 1;
  float vsum[4][4], vsq[4][4];
#pragma unroll
  for (int i = 0; i < 4; i++)
#pragma unroll
    for (int r = 0; r < 4; r++) { vsum[i][r] = 0.f; vsq[i][r] = 0.f; }
#pragma unroll
  for (int j = 0; j < 8; j++) {
    const int col = wn + j * 16 + lr;
    const float bv = bias[col];
#pragma unroll
    for (int i = 0; i < 4; i++)
#pragma unroll
      for (int r = 0; r < 4; r++) {
        const int grow = rb + i * 16 + r;
        float v = acc[i][j][r] + bv + bf2f(res[(size_t)grow * 256 + col]);
        acc[i][j][r] = v;
        vsum[i][r] += v;
        vsq[i][r]  += v * v;
      }
  }
#pragma unroll
  for (int m = 1; m <= 8; m <<= 1)
#pragma unroll
    for (int i = 0; i < 4; i++)
#pragma unroll
      for (int r = 0; r < 4; r++) {
        vsum[i][r] += __shfl_xor(vsum[i][r], m, 64);
        vsq[i][r]  += __shfl_xor(vsq[i][r],  m, 64);
      }
  if (lr == 0) {
#pragma unroll
    for (int i = 0; i < 4; i++)
#pragma unroll
      for (int r = 0; r < 4; r++) {
        const int lrow = wm + i * 16 + lq * 4 + r;
        red[wnIdx * 128 + lrow]       = vsum[i][r];
        red[256 + wnIdx * 128 + lrow] = vsq[i][r];
      }
  }
  __syncthreads();
  float mu[4][4], rstd[4][4];
#pragma unroll
  for (int i = 0; i < 4; i++)
#pragma unroll
    for (int r = 0; r < 4; r++) {
      const int lrow = wm + i * 16 + lq * 4 + r;
      const float ts = vsum[i][r] + red[(1 - wnIdx) * 128 + lrow];
      const float tq = vsq[i][r]  + red[256 + (1 - wnIdx) * 128 + lrow];
      const float m_ = ts * (1.f / 256.f);
      float var = tq * (1.f / 256.f) - m_ * m_;
      mu[i][r] = m_;
      rstd[i][r] = rsqrtf(var + 1e-5f);
    }
#pragma unroll
  for (int j = 0; j < 8; j++) {
    const int col = wn + j * 16 + lr;
    const float gg = gamma[col], bb = beta[col];
#pragma unroll
    for (int i = 0; i < 4; i++)
#pragma unroll
      for (int r = 0; r < 4; r++) {
        const int grow = rb + i * 16 + r;
        const float y = (acc[i][j][r] - mu[i][r]) * rstd[i][r] * gg + bb;
        if (MODE == 1) ((unsigned short*)outp)[(size_t)grow * 256 + col] = f2bf(y);
        else           ((float*)outp)[(size_t)grow * 256 + col] = y;
      }
  }
}

__global__ __launch_bounds__(256, 2) void out_ln_kernel(
    const unsigned short* __restrict__ A, const unsigned short* __restrict__ Bt,
    const float* __restrict__ bias, const unsigned short* __restrict__ res,
    const float* __restrict__ gamma, const float* __restrict__ beta,
    unsigned short* __restrict__ C) {
  __shared__ unsigned short As[2 * 5120];
  __shared__ unsigned short Bs[2 * 10240];
  big_body<256, 1>(As, Bs, A, Bt, bias, res, gamma, beta, C, 256, blockIdx.x, 0);
}

// ---- fused FFN: h(64x256) -> relu(hW1+b1) chunks -> xW2 +b2 +res(h) -> LN2 -> f32
// BM=64, 256 threads (4 waves, all share rows; wave w owns output cols [w*64,w*64+64)).
// Hidden never touches HBM. W1t/W2t fragments read directly (L2-resident).
__global__ __launch_bounds__(256, 2) void ffn_fused_kernel(
    const unsigned short* __restrict__ h,     // [TOKS][256] bf16 (LN1 out)
    const unsigned short* __restrict__ W1t,   // [1024][256]
    const unsigned short* __restrict__ W2t,   // [256][1024]
    const float* __restrict__ b1, const float* __restrict__ b2,
    const float* __restrict__ gamma, const float* __restrict__ beta,
    float* __restrict__ out) {
  __shared__ unsigned short Ah[64 * 264];     // h tile, pitch 264 (33.8KB)
  __shared__ unsigned short Hc[64 * 136];     // hidden chunk, pitch 136 (17.4KB)
  __shared__ float red[2][4][64];             // LN cross-wave partials (2KB)
  const int t = threadIdx.x;
  const int w = t >> 6, lane = t & 63;
  const int lr = lane & 15, lq = lane >> 4;
  const size_t rowbase = (size_t)blockIdx.x * 64;

  // stage h tile (coalesced uint4), pitch 264 for conflict-free fragment reads
  {
    const uint4* gsrc = (const uint4*)(h + rowbase * 256);
#pragma unroll
    for (int u = 0; u < 8; u++) {
      const int idx = u * 256 + t;
      const int row = idx >> 5, c8 = idx & 31;
      *(uint4*)&Ah[row * 264 + c8 * 8] = gsrc[idx];
    }
  }
  __syncthreads();

  f32x4 acc2[4][4] = {};
  const int c1base = w * 32;                  // wave's col slice within 128-chunk
#pragma unroll 1
  for (int c2 = 0; c2 < 8; c2++) {            // 8 chunks of 128 hidden cols
    f32x4 acc1[4][2] = {};
    // GEMM1: K=256, prefetch next-step W1 fragments (R2 idiom)
    const size_t w1r0 = (size_t)(c2 * 128 + c1base + lr) * 256;
    const size_t w1r1 = (size_t)(c2 * 128 + c1base + 16 + lr) * 256;
    bf16x8 bfn0 = *(const bf16x8*)&W1t[w1r0 + lq * 8];
    bf16x8 bfn1 = *(const bf16x8*)&W1t[w1r1 + lq * 8];
#pragma unroll 1
    for (int ks = 0; ks < 8; ks++) {
      const int k0 = ks * 32;
      bf16x8 b0 = bfn0, b1v = bfn1;
      if (ks < 7) {
        bfn0 = *(const bf16x8*)&W1t[w1r0 + k0 + 32 + lq * 8];
        bfn1 = *(const bf16x8*)&W1t[w1r1 + k0 + 32 + lq * 8];
      }
      bf16x8 af[4];
#pragma unroll
      for (int i = 0; i < 4; i++)
        af[i] = *(const bf16x8*)&Ah[(i * 16 + lr) * 264 + k0 + lq * 8];
#pragma unroll
      for (int i = 0; i < 4; i++) {
        acc1[i][0] = __builtin_amdgcn_mfma_f32_16x16x32_bf16(af[i], b0,  acc1[i][0], 0, 0, 0);
        acc1[i][1] = __builtin_amdgcn_mfma_f32_16x16x32_bf16(af[i], b1v, acc1[i][1], 0, 0, 0);
      }
    }
    // relu+bias -> bf16 hidden chunk into LDS (C-layout scatter)
    __syncthreads();                          // prev chunk's G2 reads of Hc done
#pragma unroll
    for (int j = 0; j < 2; j++) {
      const int colc = c1base + j * 16 + lr;
      const float bv = b1[c2 * 128 + colc];
#pragma unroll
      for (int i = 0; i < 4; i++)
#pragma unroll
        for (int r = 0; r < 4; r++)
          Hc[(i * 16 + lq * 4 + r) * 136 + colc] = f2bf(fmaxf(acc1[i][j][r] + bv, 0.f));
    }
    __syncthreads();
    // GEMM2 partial: K2=128 (4 steps), prefetch W2 fragments
    const size_t w2base = (size_t)(w * 64 + lr) * 1024 + c2 * 128;
    bf16x8 cfn0 = *(const bf16x8*)&W2t[w2base + lq * 8];
    bf16x8 cfn1 = *(const bf16x8*)&W2t[w2base + 16 * 1024 + lq * 8];
    bf16x8 cfn2 = *(const bf16x8*)&W2t[w2base + 32 * 1024 + lq * 8];
    bf16x8 cfn3 = *(const bf16x8*)&W2t[w2base + 48 * 1024 + lq * 8];
#pragma unroll 1
    for (int ks = 0; ks < 4; ks++) {
      const int k2 = ks * 32;
      bf16x8 c0 = cfn0, c1 = cfn1, c2v = cfn2, c3 = cfn3;
      if (ks < 3) {
        cfn0 = *(const bf16x8*)&W2t[w2base + k2 + 32 + lq * 8];
        cfn1 = *(const bf16x8*)&W2t[w2base + 16 * 1024 + k2 + 32 + lq * 8];
        cfn2 = *(const bf16x8*)&W2t[w2base + 32 * 1024 + k2 + 32 + lq * 8];
        cfn3 = *(const bf16x8*)&W2t[w2base + 48 * 1024 + k2 + 32 + lq * 8];
      }
      bf16x8 af2[4];
#pragma unroll
      for (int i = 0; i < 4; i++)
        af2[i] = *(const bf16x8*)&Hc[(i * 16 + lr) * 136 + k2 + lq * 8];
#pragma unroll
      for (int i = 0; i < 4; i++) {
        acc2[i][0] = __builtin_amdgcn_mfma_f32_16x16x32_bf16(af2[i], c0,  acc2[i][0], 0, 0, 0);
        acc2[i][1] = __builtin_amdgcn_mfma_f32_16x16x32_bf16(af2[i], c1,  acc2[i][1], 0, 0, 0);
        acc2[i][2] = __builtin_amdgcn_mfma_f32_16x16x32_bf16(af2[i], c2v, acc2[i][2], 0, 0, 0);
        acc2[i][3] = __builtin_amdgcn_mfma_f32_16x16x32_bf16(af2[i], c3,  acc2[i][3], 0, 0, 0);
      }
    }
  }
  // epilogue: +b2 +res(h from LDS) ; LN2 ; f32 out
  float vsum[4][4], vsq[4][4];
#pragma unroll
  for (int i = 0; i < 4; i++)
#pragma unroll
    for (int r = 0; r < 4; r++) { vsum[i][r] = 0.f; vsq[i][r] = 0.f; }
#pragma unroll
  for (int j = 0; j < 4; j++) {
    const int col = w * 64 + j * 16 + lr;
    const float bv = b2[col];
#pragma unroll
    for (int i = 0; i < 4; i++)
#pragma unroll
      for (int r = 0; r < 4; r++) {
        const int row = i * 16 + lq * 4 + r;
        float v = acc2[i][j][r] + bv + bf2f(Ah[row * 264 + col]);
        acc2[i][j][r] = v;
        vsum[i][r] += v;
        vsq[i][r]  += v * v;
      }
  }
#pragma unroll
  for (int m = 1; m <= 8; m <<= 1)
#pragma unroll
    for (int i = 0; i < 4; i++)
#pragma unroll
      for (int r = 0; r < 4; r++) {
        vsum[i][r] += __shfl_xor(vsum[i][r], m, 64);
        vsq[i][r]  += __shfl_xor(vsq[i][r],  m, 64);
      }
  if (lr == 0) {
#pragma unroll
    for (int i = 0; i < 4; i++)
#pragma unroll
      for (int r = 0; r < 4; r++) {
        const int row = i * 16 + lq * 4 + r;
        red[0][w][row] = vsum[i][r];
        red[1][w][row] = vsq[i][r];
      }
  }
  __syncthreads();
  float mu[4][4], rstd[4][4];
#pragma unroll
  for (int i = 0; i < 4; i++)
#pragma unroll
    for (int r = 0; r < 4; r++) {
      const int row = i * 16 + lq * 4 + r;
      const float ts = red[0][0][row] + red[0][1][row] + red[0][2][row] + red[0][3][row];
      const float tq = red[1][0][row] + red[1][1][row] + red[1][2][row] + red[1][3][row];
      const float m_ = ts * (1.f / 256.f);
      mu[i][r] = m_;
      rstd[i][r] = rsqrtf(tq * (1.f / 256.f) - m_ * m_ + 1e-5f);
    }
#pragma unroll
  for (int j = 0; j < 4; j++) {
    const int col = w * 64 + j * 16 + lr;
    const float gg = gamma[col], bb = beta[col];
#pragma unroll
    for (int i = 0; i < 4; i++)
#pragma unroll
      for (int r = 0; r < 4; r++) {
        const int row = i * 16 + lq * 4 + r;
        out[(rowbase + row) * 256 + col] = (acc2[i][j][r] - mu[i][r]) * rstd[i][r] * gg + bb;
      }
  }
}

// ---- bf16x8 (uint4) fused unpack+FMA into fp32 acc
__device__ __forceinline__ void fma8(uint4 v, float w, float* a) {
  const unsigned uu[4] = {v.x, v.y, v.z, v.w};
#pragma unroll
  for (int i = 0; i < 4; i++) {
    union { unsigned u; float f; } lo, hi;
    lo.u = uu[i] << 16;
    hi.u = uu[i] & 0xffff0000u;
    a[2 * i]     += w * lo.f;
    a[2 * i + 1] += w * hi.f;
  }
}

// ---- deformable attention (R0 exact): two-phase, int4 byte-offset tables
__global__ __launch_bounds__(256) void deform_kernel(const unsigned short* __restrict__ valb,
                                                     const unsigned short* __restrict__ oab,
                                                     const float* __restrict__ refp,
                                                     unsigned short* __restrict__ outb) {
  __shared__ float4 sW[8][8][17];
  __shared__ int4   sI[8][8][17];
  const int t = threadIdx.x;
  const int bid = blockIdx.x;
  const int nb = (bid & 7) * 680 + (bid >> 3);
  const int tok0 = nb * 8;

  {
    const int g = t >> 5, h = (t >> 2) & 7, l = t & 3;
    const int tok = tok0 + g;
    const unsigned short* lg = oab + (size_t)tok * 384 + 256 + h * 16;
    uint4 lv0 = ((const uint4*)lg)[0];
    uint4 lv1 = ((const uint4*)lg)[1];
    const unsigned lw[8] = {lv0.x, lv0.y, lv0.z, lv0.w, lv1.x, lv1.y, lv1.z, lv1.w};
    float w[16];
#pragma unroll
    for (int i = 0; i < 8; i++) {
      union { unsigned u; float f; } lo, hi;
      lo.u = lw[i] << 16; hi.u = lw[i] & 0xffff0000u;
      w[2 * i] = lo.f; w[2 * i + 1] = hi.f;
    }
    float mx = -1e30f;
#pragma unroll
    for (int i = 0; i < 16; i++) mx = fmaxf(mx, w[i]);
    float s = 0.f;
#pragma unroll
    for (int i = 0; i < 16; i++) { w[i] = __expf(w[i] - mx); s += w[i]; }
    const float inv = 1.f / s;
    uint4 ov = *(const uint4*)(oab + (size_t)tok * 384 + h * 32 + l * 8);
    const unsigned owv[4] = {ov.x, ov.y, ov.z, ov.w};
    float off[8];
#pragma unroll
    for (int i = 0; i < 4; i++) {
      union { unsigned u; float f; } lo, hi;
      lo.u = owv[i] << 16; hi.u = owv[i] & 0xffff0000u;
      off[2 * i] = lo.f; off[2 * i + 1] = hi.f;
    }
    const float* rp = refp + (size_t)tok * 8 + l * 2;
    const int S = 128 >> l;
    const float Sf = (float)S;
    const float rx = rp[0] * Sf - 0.5f;
    const float ry = rp[1] * Sf - 0.5f;
#pragma unroll
    for (int p = 0; p < 4; p++) {
      const int idx = l * 4 + p;
      const float x = rx + off[p * 2 + 0];
      const float y = ry + off[p * 2 + 1];
      const float aw = w[idx] * inv;
      const float x0f = floorf(x), y0f = floorf(y);
      const int x0 = (int)x0f, y0 = (int)y0f;
      const float fx = x - x0f, fy = y - y0f;
      const bool xin0 = (x0 >= 0) & (x0 < S), xin1 = (x0 + 1 >= 0) & (x0 + 1 < S);
      const bool yin0 = (y0 >= 0) & (y0 < S), yin1 = (y0 + 1 >= 0) & (y0 + 1 < S);
      const int xc0 = min(max(x0, 0), S - 1), xc1 = min(max(x0 + 1, 0), S - 1);
      const int yc0 = min(max(y0, 0), S - 1), yc1 = min(max(y0 + 1, 0), S - 1);
      sW[g][h][idx] = make_float4(aw * (1.f - fx) * (1.f - fy) * (float)(xin0 & yin0),
                                  aw * fx * (1.f - fy)         * (float)(xin1 & yin0),
                                  aw * (1.f - fx) * fy         * (float)(xin0 & yin1),
                                  aw * fx * fy                 * (float)(xin1 & yin1));
      sI[g][h][idx] = make_int4((yc0 * S + xc0) << 9, (yc0 * S + xc1) << 9,
                                (yc1 * S + xc0) << 9, (yc1 * S + xc1) << 9);
    }
  }
  __syncthreads();

  const int g = t >> 5, h = (t >> 2) & 7, dc = t & 3;
  const int tok = tok0 + g;
  const int b = tok / LQN;
  float acc[8] = {0.f, 0.f, 0.f, 0.f, 0.f, 0.f, 0.f, 0.f};
  const int ST[4] = {0, 16384, 20480, 21504};
#pragma unroll
  for (int l = 0; l < 4; l++) {
    const char* vbc = (const char*)(valb + ((size_t)(b * LQN + ST[l])) * 256 + h * 32 + dc * 8);
#pragma unroll
    for (int p = 0; p < 4; p++) {
      float4 W4 = sW[g][h][l * 4 + p];
      int4   I4 = sI[g][h][l * 4 + p];
      uint4 v00 = *(const uint4*)(vbc + I4.x);
      uint4 v10 = *(const uint4*)(vbc + I4.y);
      uint4 v01 = *(const uint4*)(vbc + I4.z);
      uint4 v11 = *(const uint4*)(vbc + I4.w);
      fma8(v00, W4.x, acc);
      fma8(v10, W4.y, acc);
      fma8(v01, W4.z, acc);
      fma8(v11, W4.w, acc);
    }
  }
  unsigned o[4];
#pragma unroll
  for (int i = 0; i < 4; i++)
    o[i] = (unsigned)f2bf(acc[2 * i]) | ((unsigned)f2bf(acc[2 * i + 1]) << 16);
  *(uint4*)(outb + (size_t)tok * 256 + h * 32 + dc * 8) = make_uint4(o[0], o[1], o[2], o[3]);
}

extern "C" void kernel_launch(void* const* d_in, const int* in_sizes, int n_in,
                              void* d_out, int out_size, void* d_ws, size_t ws_size,
                              hipStream_t stream) {
  (void)in_sizes; (void)n_in; (void)out_size; (void)ws_size;
  const float* src    = (const float*)d_in[0];
  const float* pos    = (const float*)d_in[1];
  const float* refp   = (const float*)d_in[2];
  const float* W_off  = (const float*)d_in[3];
  const float* b_off  = (const float*)d_in[4];
  const float* W_attn = (const float*)d_in[5];
  const float* b_attn = (const float*)d_in[6];
  const float* W_val  = (const float*)d_in[7];
  const float* b_val  = (const float*)d_in[8];
  const float* W_out  = (const float*)d_in[9];
  const float* b_out  = (const float*)d_in[10];
  const float* ln1_g  = (const float*)d_in[11];
  const float* ln1_b  = (const float*)d_in[12];
  const float* W1     = (const float*)d_in[13];
  const float* b1     = (const float*)d_in[14];
  const float* W2     = (const float*)d_in[15];
  const float* b2     = (const float*)d_in[16];
  const float* ln2_g  = (const float*)d_in[17];
  const float* ln2_b  = (const float*)d_in[18];

  char* ws = (char*)d_ws;
  unsigned short* Wt_val = (unsigned short*)ws;          // 65536
  unsigned short* Wt_oa  = Wt_val + 65536;               // 98304
  unsigned short* Wt_out = Wt_oa + 98304;                // 65536
  unsigned short* Wt_1   = Wt_out + 65536;               // 262144
  unsigned short* Wt_2   = Wt_1 + 262144;                // 262144
  float*          b_oa   = (float*)(Wt_2 + 262144);      // 384
  const size_t WPOOL = 2u * 1024 * 1024;

  const size_t SZ_bf = (size_t)TOKS * 256 * 2;           // 22.3 MB
  const size_t SZ_oa = (size_t)TOKS * 384 * 2;           // 33.4 MB

  unsigned short* srcb = (unsigned short*)(ws + WPOOL);
  unsigned short* qb   = (unsigned short*)(ws + WPOOL + SZ_bf);
  unsigned short* valb = (unsigned short*)(ws + WPOOL + 2 * SZ_bf);
  unsigned short* oab  = (unsigned short*)(ws + WPOOL + 3 * SZ_bf);
  unsigned short* h_bf = (unsigned short*)(ws + WPOOL + 3 * SZ_bf + SZ_oa);
  // alias (lifetime-disjoint):
  unsigned short* attnoutb = qb;     // deform out; qb dead after proj

  // 1. prep + weight transposes + bias concat
  prewt_kernel<<<13826, 256, 0, stream>>>(src, pos, srcb, qb,
                                          W_val, W_off, W_attn, W_out, W1, W2, b_off, b_attn,
                                          Wt_val, Wt_oa, Wt_out, Wt_1, Wt_2, b_oa);

  // 2. merged projections: value (N=256) + off/attn (N=384)
  proj_kernel<<<dim3(340, 5), 256, 0, stream>>>(srcb, qb, Wt_val, Wt_oa, b_val, b_oa,
                                                valb, oab);

  // 3. deformable attention (8 tokens/block, XCD-swizzled)
  deform_kernel<<<TOKS / 8, 256, 0, stream>>>(valb, oab, refp, attnoutb);

  // 4. out-proj + residual(src) + LN1 fused -> h_bf (bf16)
  out_ln_kernel<<<340, 256, 0, stream>>>(attnoutb, Wt_out, b_out, srcb, ln1_g, ln1_b, h_bf);

  // 5. fused FFN (W1+relu -> W2 + residual(h) + LN2) -> d_out (f32); hidden stays on-chip
  ffn_fused_kernel<<<680, 256, 0, stream>>>(h_bf, Wt_1, Wt_2, b1, b2, ln2_g, ln2_b,
                                            (float*)d_out);
}

// Round 7
// 431.998 us; speedup vs baseline: 1.0731x; 1.0083x over previous
//
#include <hip/hip_runtime.h>

typedef __bf16 bf16x8 __attribute__((ext_vector_type(8)));
typedef float f32x4 __attribute__((ext_vector_type(4)));

static constexpr int TOKS = 43520;   // B * LQ
static constexpr int LQN  = 21760;

__device__ __forceinline__ unsigned short f2bf(float f) {
  union { float f; unsigned u; } v; v.f = f;
  return (unsigned short)((v.u + 0x7fffu + ((v.u >> 16) & 1u)) >> 16);
}
__device__ __forceinline__ float bf2f(unsigned short b) {
  union { unsigned u; float f; } v; v.u = ((unsigned)b) << 16; return v.f;
}

// ---- fused prep + weight transpose + bias concat (one launch)
__global__ __launch_bounds__(256) void prewt_kernel(
    const float* __restrict__ src, const float* __restrict__ pos,
    unsigned short* __restrict__ srcb, unsigned short* __restrict__ qb,
    const float* __restrict__ W_val, const float* __restrict__ W_off,
    const float* __restrict__ W_attn, const float* __restrict__ W_out,
    const float* __restrict__ W1, const float* __restrict__ W2,
    const float* __restrict__ b_off, const float* __restrict__ b_attn,
    unsigned short* __restrict__ Wt_val, unsigned short* __restrict__ Wt_oa,
    unsigned short* __restrict__ Wt_out,
    unsigned short* __restrict__ Wt_1, unsigned short* __restrict__ Wt_2,
    float* __restrict__ b_oa) {
  const int bid = blockIdx.x;
  if (bid < 10880) {
    int i = bid * 256 + threadIdx.x;
    float4 s = ((const float4*)src)[i], p = ((const float4*)pos)[i];
    ((ushort4*)srcb)[i] = make_ushort4(f2bf(s.x), f2bf(s.y), f2bf(s.z), f2bf(s.w));
    ((ushort4*)qb)[i]   = make_ushort4(f2bf(s.x + p.x), f2bf(s.y + p.y),
                                       f2bf(s.z + p.z), f2bf(s.w + p.w));
    return;
  }
  int gid = (bid - 10880) * 256 + threadIdx.x;
  if (gid >= 754048) return;
  if (gid >= 753664) {
    int i = gid - 753664;
    b_oa[i] = (i < 256) ? b_off[i] : b_attn[i - 256];
    return;
  }
  const float* W; unsigned short* Wt; int idx, K, nsh;
  if (gid < 65536)       { W = W_val;  Wt = Wt_val;          idx = gid;          K = 256;  nsh = 8;  }
  else if (gid < 131072) { W = W_off;  Wt = Wt_oa;           idx = gid - 65536;  K = 256;  nsh = 8;  }
  else if (gid < 163840) { W = W_attn; Wt = Wt_oa + 65536;   idx = gid - 131072; K = 256;  nsh = 7;  }
  else if (gid < 229376) { W = W_out;  Wt = Wt_out;          idx = gid - 163840; K = 256;  nsh = 8;  }
  else if (gid < 491520) { W = W1;     Wt = Wt_1;            idx = gid - 229376; K = 256;  nsh = 10; }
  else                   { W = W2;     Wt = Wt_2;            idx = gid - 491520; K = 1024; nsh = 8;  }
  int k = idx >> nsh, n = idx & ((1 << nsh) - 1);
  Wt[n * K + k] = f2bf(W[idx]);
}

// ---- R2-proven 128x128 GEMM body: padded LDS, reg staging, ONE barrier per K-iter.
template <int K, int OUTOP>
__device__ __forceinline__ void gemm_body(unsigned short* __restrict__ As,
                                          unsigned short* __restrict__ Bs,
                                          const unsigned short* __restrict__ A,
                                          const unsigned short* __restrict__ Bt,
                                          const float* __restrict__ bias,
                                          const unsigned short* __restrict__ res,
                                          unsigned short* __restrict__ Cp,
                                          int N, int bm, int bn) {
  const int t = threadIdx.x;
  const int wave = t >> 6, lane = t & 63;
  const int wm = (wave & 1) << 6, wn = (wave >> 1) << 6;
  const int lr = lane & 15, lq = lane >> 4;
  const int row0 = t >> 2, cb0 = (t & 3) << 3;
  f32x4 acc[4][4] = {};
  const unsigned short* ga = A  + (size_t)(bm * 128 + row0) * K + cb0;
  const unsigned short* gb = Bt + (size_t)(bn * 128 + row0) * K + cb0;
  const size_t gs = (size_t)64 * K;
  uint4 pa0 = *(const uint4*)ga;
  uint4 pa1 = *(const uint4*)(ga + gs);
  uint4 pb0 = *(const uint4*)gb;
  uint4 pb1 = *(const uint4*)(gb + gs);
  int p = 0;
#pragma unroll 1
  for (int k0 = 0; k0 < K; k0 += 32) {
    unsigned short* Ab = As + p * 5120;
    unsigned short* Bb = Bs + p * 5120;
    *(uint4*)&Ab[row0 * 40 + cb0] = pa0;
    *(uint4*)&Ab[(row0 + 64) * 40 + cb0] = pa1;
    *(uint4*)&Bb[row0 * 40 + cb0] = pb0;
    *(uint4*)&Bb[(row0 + 64) * 40 + cb0] = pb1;
    __syncthreads();
    if (k0 + 32 < K) {
      pa0 = *(const uint4*)(ga + k0 + 32);
      pa1 = *(const uint4*)(ga + gs + k0 + 32);
      pb0 = *(const uint4*)(gb + k0 + 32);
      pb1 = *(const uint4*)(gb + gs + k0 + 32);
    }
    bf16x8 af[4], bfr[4];
#pragma unroll
    for (int i = 0; i < 4; i++) af[i] = *(const bf16x8*)&Ab[(wm + i * 16 + lr) * 40 + lq * 8];
#pragma unroll
    for (int j = 0; j < 4; j++) bfr[j] = *(const bf16x8*)&Bb[(wn + j * 16 + lr) * 40 + lq * 8];
#pragma unroll
    for (int i = 0; i < 4; i++)
#pragma unroll
      for (int j = 0; j < 4; j++)
        acc[i][j] = __builtin_amdgcn_mfma_f32_16x16x32_bf16(af[i], bfr[j], acc[i][j], 0, 0, 0);
    p ^= 1;
  }
  const int rb = bm * 128 + wm + lq * 4;
  const int cbase = bn * 128 + wn + lr;
#pragma unroll
  for (int j = 0; j < 4; j++) {
    const int col = cbase + j * 16;
    const float bv = bias[col];
#pragma unroll
    for (int i = 0; i < 4; i++) {
#pragma unroll
      for (int r = 0; r < 4; r++) {
        float v = acc[i][j][r] + bv;
        size_t o = (size_t)(rb + i * 16 + r) * N + col;
        if (OUTOP == 1) Cp[o] = f2bf(v);
        else if (OUTOP == 2) Cp[o] = f2bf(fmaxf(v, 0.f));
        else Cp[o] = f2bf(v + bf2f(res[o]));
      }
    }
  }
}

__global__ __launch_bounds__(256) void proj_kernel(
    const unsigned short* __restrict__ srcb, const unsigned short* __restrict__ qb,
    const unsigned short* __restrict__ Wt_val, const unsigned short* __restrict__ Wt_oa,
    const float* __restrict__ b_val, const float* __restrict__ b_oa,
    unsigned short* __restrict__ valb, unsigned short* __restrict__ oab) {
  __shared__ unsigned short As[2 * 5120];
  __shared__ unsigned short Bs[2 * 5120];
  const int bn = blockIdx.y;
  if (bn < 2)
    gemm_body<256, 1>(As, Bs, srcb, Wt_val, b_val, nullptr, valb, 256, blockIdx.x, bn);
  else
    gemm_body<256, 1>(As, Bs, qb, Wt_oa, b_oa, nullptr, oab, 384, blockIdx.x, bn - 2);
}

// ---- fused tail: out-proj + residual(src) + LN1 + FFN(W1,relu,W2) + residual(h) + LN2.
// BM=64, 256 threads (4 waves); wave w owns output cols [w*64, w*64+64).
// h and hidden never touch HBM. All weight fragments read directly (L2-resident).
__global__ __launch_bounds__(256, 2) void fused_tail_kernel(
    const unsigned short* __restrict__ attn,  // [TOKS][256] deform out (bf16)
    const unsigned short* __restrict__ Wot,   // W_out^T [256][256]
    const float* __restrict__ b_out,
    const unsigned short* __restrict__ srcres,// srcb residual [TOKS][256]
    const float* __restrict__ g1, const float* __restrict__ be1,
    const unsigned short* __restrict__ W1t,   // [1024][256]
    const unsigned short* __restrict__ W2t,   // [256][1024]
    const float* __restrict__ b1, const float* __restrict__ b2,
    const float* __restrict__ g2, const float* __restrict__ be2,
    float* __restrict__ out) {
  __shared__ unsigned short Ah[64 * 264];     // attn tile, then h tile (33.8KB)
  __shared__ unsigned short Hc[64 * 136];     // hidden chunk (17.4KB)
  __shared__ float red[2][4][64];             // cross-wave LN partials (2KB)
  const int t = threadIdx.x;
  const int w = t >> 6, lane = t & 63;
  const int lr = lane & 15, lq = lane >> 4;
  const size_t rowbase = (size_t)blockIdx.x * 64;

  // stage attn tile (coalesced uint4), pitch 264
  {
    const uint4* gsrc = (const uint4*)(attn + rowbase * 256);
#pragma unroll
    for (int u = 0; u < 8; u++) {
      const int idx = u * 256 + t;
      const int row = idx >> 5, c8 = idx & 31;
      *(uint4*)&Ah[row * 264 + c8 * 8] = gsrc[idx];
    }
  }
  __syncthreads();

  // ---- GEMM0: out-proj (K=256); wave w -> 64 cols, 4 col-frags
  f32x4 acc0[4][4] = {};
  {
    const size_t wb = (size_t)(w * 64 + lr) * 256;
    bf16x8 pf0 = *(const bf16x8*)&Wot[wb + lq * 8];
    bf16x8 pf1 = *(const bf16x8*)&Wot[wb + 16 * 256 + lq * 8];
    bf16x8 pf2 = *(const bf16x8*)&Wot[wb + 32 * 256 + lq * 8];
    bf16x8 pf3 = *(const bf16x8*)&Wot[wb + 48 * 256 + lq * 8];
#pragma unroll 1
    for (int ks = 0; ks < 8; ks++) {
      const int k0 = ks * 32;
      bf16x8 c0 = pf0, c1 = pf1, c2 = pf2, c3 = pf3;
      if (ks < 7) {
        pf0 = *(const bf16x8*)&Wot[wb + k0 + 32 + lq * 8];
        pf1 = *(const bf16x8*)&Wot[wb + 16 * 256 + k0 + 32 + lq * 8];
        pf2 = *(const bf16x8*)&Wot[wb + 32 * 256 + k0 + 32 + lq * 8];
        pf3 = *(const bf16x8*)&Wot[wb + 48 * 256 + k0 + 32 + lq * 8];
      }
      bf16x8 af[4];
#pragma unroll
      for (int i = 0; i < 4; i++)
        af[i] = *(const bf16x8*)&Ah[(i * 16 + lr) * 264 + k0 + lq * 8];
#pragma unroll
      for (int i = 0; i < 4; i++) {
        acc0[i][0] = __builtin_amdgcn_mfma_f32_16x16x32_bf16(af[i], c0, acc0[i][0], 0, 0, 0);
        acc0[i][1] = __builtin_amdgcn_mfma_f32_16x16x32_bf16(af[i], c1, acc0[i][1], 0, 0, 0);
        acc0[i][2] = __builtin_amdgcn_mfma_f32_16x16x32_bf16(af[i], c2, acc0[i][2], 0, 0, 0);
        acc0[i][3] = __builtin_amdgcn_mfma_f32_16x16x32_bf16(af[i], c3, acc0[i][3], 0, 0, 0);
      }
    }
  }
  // ---- epilogue0: +b_out +res(src) ; LN1 stats ; h -> Ah (bf16, in place)
  {
    float vsum[4][4], vsq[4][4];
#pragma unroll
    for (int i = 0; i < 4; i++)
#pragma unroll
      for (int r = 0; r < 4; r++) { vsum[i][r] = 0.f; vsq[i][r] = 0.f; }
#pragma unroll
    for (int j = 0; j < 4; j++) {
      const int col = w * 64 + j * 16 + lr;
      const float bv = b_out[col];
#pragma unroll
      for (int i = 0; i < 4; i++)
#pragma unroll
        for (int r = 0; r < 4; r++) {
          const int row = i * 16 + lq * 4 + r;
          float v = acc0[i][j][r] + bv + bf2f(srcres[(rowbase + row) * 256 + col]);
          acc0[i][j][r] = v;
          vsum[i][r] += v;
          vsq[i][r]  += v * v;
        }
    }
#pragma unroll
    for (int m = 1; m <= 8; m <<= 1)
#pragma unroll
      for (int i = 0; i < 4; i++)
#pragma unroll
        for (int r = 0; r < 4; r++) {
          vsum[i][r] += __shfl_xor(vsum[i][r], m, 64);
          vsq[i][r]  += __shfl_xor(vsq[i][r],  m, 64);
        }
    if (lr == 0) {
#pragma unroll
      for (int i = 0; i < 4; i++)
#pragma unroll
        for (int r = 0; r < 4; r++) {
          const int row = i * 16 + lq * 4 + r;
          red[0][w][row] = vsum[i][r];
          red[1][w][row] = vsq[i][r];
        }
    }
    __syncthreads();                    // red ready; all GEMM0 Ah reads done
    float mu[4][4], rstd[4][4];
#pragma unroll
    for (int i = 0; i < 4; i++)
#pragma unroll
      for (int r = 0; r < 4; r++) {
        const int row = i * 16 + lq * 4 + r;
        const float ts = red[0][0][row] + red[0][1][row] + red[0][2][row] + red[0][3][row];
        const float tq = red[1][0][row] + red[1][1][row] + red[1][2][row] + red[1][3][row];
        const float m_ = ts * (1.f / 256.f);
        mu[i][r] = m_;
        rstd[i][r] = rsqrtf(tq * (1.f / 256.f) - m_ * m_ + 1e-5f);
      }
#pragma unroll
    for (int j = 0; j < 4; j++) {
      const int col = w * 64 + j * 16 + lr;
      const float gg = g1[col], bb = be1[col];
#pragma unroll
      for (int i = 0; i < 4; i++)
#pragma unroll
        for (int r = 0; r < 4; r++) {
          const int row = i * 16 + lq * 4 + r;
          const float y = (acc0[i][j][r] - mu[i][r]) * rstd[i][r] * gg + bb;
          Ah[row * 264 + col] = f2bf(y);
        }
    }
  }
  __syncthreads();                      // h tile complete

  // ---- FFN (R6-proven): 8 chunks of 128 hidden cols
  f32x4 acc2[4][4] = {};
  const int c1base = w * 32;
#pragma unroll 1
  for (int c2 = 0; c2 < 8; c2++) {
    f32x4 acc1[4][2] = {};
    const size_t w1r0 = (size_t)(c2 * 128 + c1base + lr) * 256;
    const size_t w1r1 = (size_t)(c2 * 128 + c1base + 16 + lr) * 256;
    bf16x8 bfn0 = *(const bf16x8*)&W1t[w1r0 + lq * 8];
    bf16x8 bfn1 = *(const bf16x8*)&W1t[w1r1 + lq * 8];
#pragma unroll 1
    for (int ks = 0; ks < 8; ks++) {
      const int k0 = ks * 32;
      bf16x8 b0 = bfn0, b1v = bfn1;
      if (ks < 7) {
        bfn0 = *(const bf16x8*)&W1t[w1r0 + k0 + 32 + lq * 8];
        bfn1 = *(const bf16x8*)&W1t[w1r1 + k0 + 32 + lq * 8];
      }
      bf16x8 af[4];
#pragma unroll
      for (int i = 0; i < 4; i++)
        af[i] = *(const bf16x8*)&Ah[(i * 16 + lr) * 264 + k0 + lq * 8];
#pragma unroll
      for (int i = 0; i < 4; i++) {
        acc1[i][0] = __builtin_amdgcn_mfma_f32_16x16x32_bf16(af[i], b0,  acc1[i][0], 0, 0, 0);
        acc1[i][1] = __builtin_amdgcn_mfma_f32_16x16x32_bf16(af[i], b1v, acc1[i][1], 0, 0, 0);
      }
    }
    __syncthreads();                    // prev chunk's GEMM2 reads of Hc done
#pragma unroll
    for (int j = 0; j < 2; j++) {
      const int colc = c1base + j * 16 + lr;
      const float bv = b1[c2 * 128 + colc];
#pragma unroll
      for (int i = 0; i < 4; i++)
#pragma unroll
        for (int r = 0; r < 4; r++)
          Hc[(i * 16 + lq * 4 + r) * 136 + colc] = f2bf(fmaxf(acc1[i][j][r] + bv, 0.f));
    }
    __syncthreads();
    const size_t w2base = (size_t)(w * 64 + lr) * 1024 + c2 * 128;
    bf16x8 cfn0 = *(const bf16x8*)&W2t[w2base + lq * 8];
    bf16x8 cfn1 = *(const bf16x8*)&W2t[w2base + 16 * 1024 + lq * 8];
    bf16x8 cfn2 = *(const bf16x8*)&W2t[w2base + 32 * 1024 + lq * 8];
    bf16x8 cfn3 = *(const bf16x8*)&W2t[w2base + 48 * 1024 + lq * 8];
#pragma unroll 1
    for (int ks = 0; ks < 4; ks++) {
      const int k2 = ks * 32;
      bf16x8 c0 = cfn0, c1 = cfn1, c2v = cfn2, c3 = cfn3;
      if (ks < 3) {
        cfn0 = *(const bf16x8*)&W2t[w2base + k2 + 32 + lq * 8];
        cfn1 = *(const bf16x8*)&W2t[w2base + 16 * 1024 + k2 + 32 + lq * 8];
        cfn2 = *(const bf16x8*)&W2t[w2base + 32 * 1024 + k2 + 32 + lq * 8];
        cfn3 = *(const bf16x8*)&W2t[w2base + 48 * 1024 + k2 + 32 + lq * 8];
      }
      bf16x8 af2[4];
#pragma unroll
      for (int i = 0; i < 4; i++)
        af2[i] = *(const bf16x8*)&Hc[(i * 16 + lr) * 136 + k2 + lq * 8];
#pragma unroll
      for (int i = 0; i < 4; i++) {
        acc2[i][0] = __builtin_amdgcn_mfma_f32_16x16x32_bf16(af2[i], c0,  acc2[i][0], 0, 0, 0);
        acc2[i][1] = __builtin_amdgcn_mfma_f32_16x16x32_bf16(af2[i], c1,  acc2[i][1], 0, 0, 0);
        acc2[i][2] = __builtin_amdgcn_mfma_f32_16x16x32_bf16(af2[i], c2v, acc2[i][2], 0, 0, 0);
        acc2[i][3] = __builtin_amdgcn_mfma_f32_16x16x32_bf16(af2[i], c3,  acc2[i][3], 0, 0, 0);
      }
    }
  }
  // ---- epilogue2: +b2 +res(h from Ah) ; LN2 ; f32 out
  float vsum[4][4], vsq[4][4];
#pragma unroll
  for (int i = 0; i < 4; i++)
#pragma unroll
    for (int r = 0; r < 4; r++) { vsum[i][r] = 0.f; vsq[i][r] = 0.f; }
#pragma unroll
  for (int j = 0; j < 4; j++) {
    const int col = w * 64 + j * 16 + lr;
    const float bv = b2[col];
#pragma unroll
    for (int i = 0; i < 4; i++)
#pragma unroll
      for (int r = 0; r < 4; r++) {
        const int row = i * 16 + lq * 4 + r;
        float v = acc2[i][j][r] + bv + bf2f(Ah[row * 264 + col]);
        acc2[i][j][r] = v;
        vsum[i][r] += v;
        vsq[i][r]  += v * v;
      }
  }
#pragma unroll
  for (int m = 1; m <= 8; m <<= 1)
#pragma unroll
    for (int i = 0; i < 4; i++)
#pragma unroll
      for (int r = 0; r < 4; r++) {
        vsum[i][r] += __shfl_xor(vsum[i][r], m, 64);
        vsq[i][r]  += __shfl_xor(vsq[i][r],  m, 64);
      }
  __syncthreads();                      // LN1-era red reads long done; safe to reuse
  if (lr == 0) {
#pragma unroll
    for (int i = 0; i < 4; i++)
#pragma unroll
      for (int r = 0; r < 4; r++) {
        const int row = i * 16 + lq * 4 + r;
        red[0][w][row] = vsum[i][r];
        red[1][w][row] = vsq[i][r];
      }
  }
  __syncthreads();
  float mu[4][4], rstd[4][4];
#pragma unroll
  for (int i = 0; i < 4; i++)
#pragma unroll
    for (int r = 0; r < 4; r++) {
      const int row = i * 16 + lq * 4 + r;
      const float ts = red[0][0][row] + red[0][1][row] + red[0][2][row] + red[0][3][row];
      const float tq = red[1][0][row] + red[1][1][row] + red[1][2][row] + red[1][3][row];
      const float m_ = ts * (1.f / 256.f);
      mu[i][r] = m_;
      rstd[i][r] = rsqrtf(tq * (1.f / 256.f) - m_ * m_ + 1e-5f);
    }
#pragma unroll
  for (int j = 0; j < 4; j++) {
    const int col = w * 64 + j * 16 + lr;
    const float gg = g2[col], bb = be2[col];
#pragma unroll
    for (int i = 0; i < 4; i++)
#pragma unroll
      for (int r = 0; r < 4; r++) {
        const int row = i * 16 + lq * 4 + r;
        out[(rowbase + row) * 256 + col] = (acc2[i][j][r] - mu[i][r]) * rstd[i][r] * gg + bb;
      }
  }
}

// ---- bf16x8 (uint4) fused unpack+FMA into fp32 acc
__device__ __forceinline__ void fma8(uint4 v, float w, float* a) {
  const unsigned uu[4] = {v.x, v.y, v.z, v.w};
#pragma unroll
  for (int i = 0; i < 4; i++) {
    union { unsigned u; float f; } lo, hi;
    lo.u = uu[i] << 16;
    hi.u = uu[i] & 0xffff0000u;
    a[2 * i]     += w * lo.f;
    a[2 * i + 1] += w * hi.f;
  }
}

// ---- deformable attention (R0 exact): two-phase, int4 byte-offset tables
__global__ __launch_bounds__(256) void deform_kernel(const unsigned short* __restrict__ valb,
                                                     const unsigned short* __restrict__ oab,
                                                     const float* __restrict__ refp,
                                                     unsigned short* __restrict__ outb) {
  __shared__ float4 sW[8][8][17];
  __shared__ int4   sI[8][8][17];
  const int t = threadIdx.x;
  const int bid = blockIdx.x;
  const int nb = (bid & 7) * 680 + (bid >> 3);
  const int tok0 = nb * 8;

  {
    const int g = t >> 5, h = (t >> 2) & 7, l = t & 3;
    const int tok = tok0 + g;
    const unsigned short* lg = oab + (size_t)tok * 384 + 256 + h * 16;
    uint4 lv0 = ((const uint4*)lg)[0];
    uint4 lv1 = ((const uint4*)lg)[1];
    const unsigned lw[8] = {lv0.x, lv0.y, lv0.z, lv0.w, lv1.x, lv1.y, lv1.z, lv1.w};
    float w[16];
#pragma unroll
    for (int i = 0; i < 8; i++) {
      union { unsigned u; float f; } lo, hi;
      lo.u = lw[i] << 16; hi.u = lw[i] & 0xffff0000u;
      w[2 * i] = lo.f; w[2 * i + 1] = hi.f;
    }
    float mx = -1e30f;
#pragma unroll
    for (int i = 0; i < 16; i++) mx = fmaxf(mx, w[i]);
    float s = 0.f;
#pragma unroll
    for (int i = 0; i < 16; i++) { w[i] = __expf(w[i] - mx); s += w[i]; }
    const float inv = 1.f / s;
    uint4 ov = *(const uint4*)(oab + (size_t)tok * 384 + h * 32 + l * 8);
    const unsigned owv[4] = {ov.x, ov.y, ov.z, ov.w};
    float off[8];
#pragma unroll
    for (int i = 0; i < 4; i++) {
      union { unsigned u; float f; } lo, hi;
      lo.u = owv[i] << 16; hi.u = owv[i] & 0xffff0000u;
      off[2 * i] = lo.f; off[2 * i + 1] = hi.f;
    }
    const float* rp = refp + (size_t)tok * 8 + l * 2;
    const int S = 128 >> l;
    const float Sf = (float)S;
    const float rx = rp[0] * Sf - 0.5f;
    const float ry = rp[1] * Sf - 0.5f;
#pragma unroll
    for (int p = 0; p < 4; p++) {
      const int idx = l * 4 + p;
      const float x = rx + off[p * 2 + 0];
      const float y = ry + off[p * 2 + 1];
      const float aw = w[idx] * inv;
      const float x0f = floorf(x), y0f = floorf(y);
      const int x0 = (int)x0f, y0 = (int)y0f;
      const float fx = x - x0f, fy = y - y0f;
      const bool xin0 = (x0 >= 0) & (x0 < S), xin1 = (x0 + 1 >= 0) & (x0 + 1 < S);
      const bool yin0 = (y0 >= 0) & (y0 < S), yin1 = (y0 + 1 >= 0) & (y0 + 1 < S);
      const int xc0 = min(max(x0, 0), S - 1), xc1 = min(max(x0 + 1, 0), S - 1);
      const int yc0 = min(max(y0, 0), S - 1), yc1 = min(max(y0 + 1, 0), S - 1);
      sW[g][h][idx] = make_float4(aw * (1.f - fx) * (1.f - fy) * (float)(xin0 & yin0),
                                  aw * fx * (1.f - fy)         * (float)(xin1 & yin0),
                                  aw * (1.f - fx) * fy         * (float)(xin0 & yin1),
                                  aw * fx * fy                 * (float)(xin1 & yin1));
      sI[g][h][idx] = make_int4((yc0 * S + xc0) << 9, (yc0 * S + xc1) << 9,
                                (yc1 * S + xc0) << 9, (yc1 * S + xc1) << 9);
    }
  }
  __syncthreads();

  const int g = t >> 5, h = (t >> 2) & 7, dc = t & 3;
  const int tok = tok0 + g;
  const int b = tok / LQN;
  float acc[8] = {0.f, 0.f, 0.f, 0.f, 0.f, 0.f, 0.f, 0.f};
  const int ST[4] = {0, 16384, 20480, 21504};
#pragma unroll
  for (int l = 0; l < 4; l++) {
    const char* vbc = (const char*)(valb + ((size_t)(b * LQN + ST[l])) * 256 + h * 32 + dc * 8);
#pragma unroll
    for (int p = 0; p < 4; p++) {
      float4 W4 = sW[g][h][l * 4 + p];
      int4   I4 = sI[g][h][l * 4 + p];
      uint4 v00 = *(const uint4*)(vbc + I4.x);
      uint4 v10 = *(const uint4*)(vbc + I4.y);
      uint4 v01 = *(const uint4*)(vbc + I4.z);
      uint4 v11 = *(const uint4*)(vbc + I4.w);
      fma8(v00, W4.x, acc);
      fma8(v10, W4.y, acc);
      fma8(v01, W4.z, acc);
      fma8(v11, W4.w, acc);
    }
  }
  unsigned o[4];
#pragma unroll
  for (int i = 0; i < 4; i++)
    o[i] = (unsigned)f2bf(acc[2 * i]) | ((unsigned)f2bf(acc[2 * i + 1]) << 16);
  *(uint4*)(outb + (size_t)tok * 256 + h * 32 + dc * 8) = make_uint4(o[0], o[1], o[2], o[3]);
}

extern "C" void kernel_launch(void* const* d_in, const int* in_sizes, int n_in,
                              void* d_out, int out_size, void* d_ws, size_t ws_size,
                              hipStream_t stream) {
  (void)in_sizes; (void)n_in; (void)out_size; (void)ws_size;
  const float* src    = (const float*)d_in[0];
  const float* pos    = (const float*)d_in[1];
  const float* refp   = (const float*)d_in[2];
  const float* W_off  = (const float*)d_in[3];
  const float* b_off  = (const float*)d_in[4];
  const float* W_attn = (const float*)d_in[5];
  const float* b_attn = (const float*)d_in[6];
  const float* W_val  = (const float*)d_in[7];
  const float* b_val  = (const float*)d_in[8];
  const float* W_out  = (const float*)d_in[9];
  const float* b_out  = (const float*)d_in[10];
  const float* ln1_g  = (const float*)d_in[11];
  const float* ln1_b  = (const float*)d_in[12];
  const float* W1     = (const float*)d_in[13];
  const float* b1     = (const float*)d_in[14];
  const float* W2     = (const float*)d_in[15];
  const float* b2     = (const float*)d_in[16];
  const float* ln2_g  = (const float*)d_in[17];
  const float* ln2_b  = (const float*)d_in[18];

  char* ws = (char*)d_ws;
  unsigned short* Wt_val = (unsigned short*)ws;          // 65536
  unsigned short* Wt_oa  = Wt_val + 65536;               // 98304
  unsigned short* Wt_out = Wt_oa + 98304;                // 65536
  unsigned short* Wt_1   = Wt_out + 65536;               // 262144
  unsigned short* Wt_2   = Wt_1 + 262144;                // 262144
  float*          b_oa   = (float*)(Wt_2 + 262144);      // 384
  const size_t WPOOL = 2u * 1024 * 1024;

  const size_t SZ_bf = (size_t)TOKS * 256 * 2;           // 22.3 MB
  const size_t SZ_oa = (size_t)TOKS * 384 * 2;           // 33.4 MB

  unsigned short* srcb = (unsigned short*)(ws + WPOOL);
  unsigned short* qb   = (unsigned short*)(ws + WPOOL + SZ_bf);
  unsigned short* valb = (unsigned short*)(ws + WPOOL + 2 * SZ_bf);
  unsigned short* oab  = (unsigned short*)(ws + WPOOL + 3 * SZ_bf);
  // alias (lifetime-disjoint):
  unsigned short* attnoutb = qb;     // deform out; qb dead after proj

  // 1. prep + weight transposes + bias concat
  prewt_kernel<<<13826, 256, 0, stream>>>(src, pos, srcb, qb,
                                          W_val, W_off, W_attn, W_out, W1, W2, b_off, b_attn,
                                          Wt_val, Wt_oa, Wt_out, Wt_1, Wt_2, b_oa);

  // 2. merged projections: value (N=256) + off/attn (N=384)
  proj_kernel<<<dim3(340, 5), 256, 0, stream>>>(srcb, qb, Wt_val, Wt_oa, b_val, b_oa,
                                                valb, oab);

  // 3. deformable attention (8 tokens/block, XCD-swizzled)
  deform_kernel<<<TOKS / 8, 256, 0, stream>>>(valb, oab, refp, attnoutb);

  // 4. fused tail: out-proj + res(src) + LN1 + FFN + res(h) + LN2 -> d_out (f32)
  fused_tail_kernel<<<680, 256, 0, stream>>>(attnoutb, Wt_out, b_out, srcb, ln1_g, ln1_b,
                                             Wt_1, Wt_2, b1, b2, ln2_g, ln2_b,
                                             (float*)d_out);
}

// Round 8
// 429.741 us; speedup vs baseline: 1.0787x; 1.0053x over previous
//
#include <hip/hip_runtime.h>

typedef __bf16 bf16x8 __attribute__((ext_vector_type(8)));
typedef float f32x4 __attribute__((ext_vector_type(4)));
typedef float f32x2 __attribute__((ext_vector_type(2)));

static constexpr int TOKS = 43520;   // B * LQ
static constexpr int LQN  = 21760;

__device__ __forceinline__ unsigned short f2bf(float f) {
  union { float f; unsigned u; } v; v.f = f;
  return (unsigned short)((v.u + 0x7fffu + ((v.u >> 16) & 1u)) >> 16);
}
__device__ __forceinline__ float bf2f(unsigned short b) {
  union { unsigned u; float f; } v; v.u = ((unsigned)b) << 16; return v.f;
}

// ---- fused prep + LDS-tiled weight transpose (coalesced stores) + bias concat
__global__ __launch_bounds__(256) void prewt_kernel(
    const float* __restrict__ src, const float* __restrict__ pos,
    unsigned short* __restrict__ srcb, unsigned short* __restrict__ qb,
    const float* __restrict__ W_val, const float* __restrict__ W_off,
    const float* __restrict__ W_attn, const float* __restrict__ W_out,
    const float* __restrict__ W1, const float* __restrict__ W2,
    const float* __restrict__ b_off, const float* __restrict__ b_attn,
    unsigned short* __restrict__ Wt_val, unsigned short* __restrict__ Wt_oa,
    unsigned short* __restrict__ Wt_out,
    unsigned short* __restrict__ Wt_1, unsigned short* __restrict__ Wt_2,
    float* __restrict__ b_oa) {
  const int bid = blockIdx.x;
  const int t = threadIdx.x;
  if (bid < 10880) {
    int i = bid * 256 + t;
    float4 s = ((const float4*)src)[i], p = ((const float4*)pos)[i];
    ((ushort4*)srcb)[i] = make_ushort4(f2bf(s.x), f2bf(s.y), f2bf(s.z), f2bf(s.w));
    ((ushort4*)qb)[i]   = make_ushort4(f2bf(s.x + p.x), f2bf(s.y + p.y),
                                       f2bf(s.z + p.z), f2bf(s.w + p.w));
    return;
  }
  if (bid == 11616) {                  // bias concat
    b_oa[t] = (t < 256) ? b_off[t] : 0.f;
    if (t >= 256) return;
    if (t < 128) b_oa[256 + t] = b_attn[t];
    return;
  }
  // ---- 32x32 tiled transpose: W [Kd][Nd] f32 -> Wt [Nd][Kd] bf16
  int tid = bid - 10880;               // 0..735
  const float* W; unsigned short* Wt; int Kd, Nd, nshn;
  if (tid < 64)        {            W = W_val;  Wt = Wt_val;         Kd = 256;  Nd = 256;  nshn = 3; }
  else if (tid < 128)  { tid -= 64; W = W_off;  Wt = Wt_oa;          Kd = 256;  Nd = 256;  nshn = 3; }
  else if (tid < 160)  { tid -= 128;W = W_attn; Wt = Wt_oa + 65536;  Kd = 256;  Nd = 128;  nshn = 2; }
  else if (tid < 224)  { tid -= 160;W = W_out;  Wt = Wt_out;         Kd = 256;  Nd = 256;  nshn = 3; }
  else if (tid < 480)  { tid -= 224;W = W1;     Wt = Wt_1;           Kd = 256;  Nd = 1024; nshn = 5; }
  else                 { tid -= 480;W = W2;     Wt = Wt_2;           Kd = 1024; Nd = 256;  nshn = 3; }
  const int k0 = (tid >> nshn) * 32;
  const int n0 = (tid & ((1 << nshn) - 1)) * 32;
  __shared__ float tileT[32][33];
  {
    const int kl = t >> 3, nc = (t & 7) * 4;
    float4 v = *(const float4*)&W[(size_t)(k0 + kl) * Nd + n0 + nc];
    tileT[nc + 0][kl] = v.x; tileT[nc + 1][kl] = v.y;
    tileT[nc + 2][kl] = v.z; tileT[nc + 3][kl] = v.w;
  }
  __syncthreads();
  {
    const int nl = t >> 3, kc = (t & 7) * 4;
    ushort4 o = make_ushort4(f2bf(tileT[nl][kc + 0]), f2bf(tileT[nl][kc + 1]),
                             f2bf(tileT[nl][kc + 2]), f2bf(tileT[nl][kc + 3]));
    *(ushort4*)&Wt[(size_t)(n0 + nl) * Kd + k0 + kc] = o;
  }
}

// ---- R2-proven 128x128 GEMM body: padded LDS, reg staging, ONE barrier per K-iter.
template <int K, int OUTOP>
__device__ __forceinline__ void gemm_body(unsigned short* __restrict__ As,
                                          unsigned short* __restrict__ Bs,
                                          const unsigned short* __restrict__ A,
                                          const unsigned short* __restrict__ Bt,
                                          const float* __restrict__ bias,
                                          const unsigned short* __restrict__ res,
                                          unsigned short* __restrict__ Cp,
                                          int N, int bm, int bn) {
  const int t = threadIdx.x;
  const int wave = t >> 6, lane = t & 63;
  const int wm = (wave & 1) << 6, wn = (wave >> 1) << 6;
  const int lr = lane & 15, lq = lane >> 4;
  const int row0 = t >> 2, cb0 = (t & 3) << 3;
  f32x4 acc[4][4] = {};
  const unsigned short* ga = A  + (size_t)(bm * 128 + row0) * K + cb0;
  const unsigned short* gb = Bt + (size_t)(bn * 128 + row0) * K + cb0;
  const size_t gs = (size_t)64 * K;
  uint4 pa0 = *(const uint4*)ga;
  uint4 pa1 = *(const uint4*)(ga + gs);
  uint4 pb0 = *(const uint4*)gb;
  uint4 pb1 = *(const uint4*)(gb + gs);
  int p = 0;
#pragma unroll 1
  for (int k0 = 0; k0 < K; k0 += 32) {
    unsigned short* Ab = As + p * 5120;
    unsigned short* Bb = Bs + p * 5120;
    *(uint4*)&Ab[row0 * 40 + cb0] = pa0;
    *(uint4*)&Ab[(row0 + 64) * 40 + cb0] = pa1;
    *(uint4*)&Bb[row0 * 40 + cb0] = pb0;
    *(uint4*)&Bb[(row0 + 64) * 40 + cb0] = pb1;
    __syncthreads();
    if (k0 + 32 < K) {
      pa0 = *(const uint4*)(ga + k0 + 32);
      pa1 = *(const uint4*)(ga + gs + k0 + 32);
      pb0 = *(const uint4*)(gb + k0 + 32);
      pb1 = *(const uint4*)(gb + gs + k0 + 32);
    }
    bf16x8 af[4], bfr[4];
#pragma unroll
    for (int i = 0; i < 4; i++) af[i] = *(const bf16x8*)&Ab[(wm + i * 16 + lr) * 40 + lq * 8];
#pragma unroll
    for (int j = 0; j < 4; j++) bfr[j] = *(const bf16x8*)&Bb[(wn + j * 16 + lr) * 40 + lq * 8];
#pragma unroll
    for (int i = 0; i < 4; i++)
#pragma unroll
      for (int j = 0; j < 4; j++)
        acc[i][j] = __builtin_amdgcn_mfma_f32_16x16x32_bf16(af[i], bfr[j], acc[i][j], 0, 0, 0);
    p ^= 1;
  }
  const int rb = bm * 128 + wm + lq * 4;
  const int cbase = bn * 128 + wn + lr;
#pragma unroll
  for (int j = 0; j < 4; j++) {
    const int col = cbase + j * 16;
    const float bv = bias[col];
#pragma unroll
    for (int i = 0; i < 4; i++) {
#pragma unroll
      for (int r = 0; r < 4; r++) {
        float v = acc[i][j][r] + bv;
        size_t o = (size_t)(rb + i * 16 + r) * N + col;
        if (OUTOP == 1) Cp[o] = f2bf(v);
        else if (OUTOP == 2) Cp[o] = f2bf(fmaxf(v, 0.f));
        else Cp[o] = f2bf(v + bf2f(res[o]));
      }
    }
  }
}

__global__ __launch_bounds__(256) void proj_kernel(
    const unsigned short* __restrict__ srcb, const unsigned short* __restrict__ qb,
    const unsigned short* __restrict__ Wt_val, const unsigned short* __restrict__ Wt_oa,
    const float* __restrict__ b_val, const float* __restrict__ b_oa,
    unsigned short* __restrict__ valb, unsigned short* __restrict__ oab) {
  __shared__ unsigned short As[2 * 5120];
  __shared__ unsigned short Bs[2 * 5120];
  const int bn = blockIdx.y;
  if (bn < 2)
    gemm_body<256, 1>(As, Bs, srcb, Wt_val, b_val, nullptr, valb, 256, blockIdx.x, bn);
  else
    gemm_body<256, 1>(As, Bs, qb, Wt_oa, b_oa, nullptr, oab, 384, blockIdx.x, bn - 2);
}

// ---- fused tail: out-proj + res(src) + LN1 + FFN + res(h) + LN2.
// Deep rolling register prefetch on all weight streams (the R7 kernel was
// latency-bound on depth-1 L2 weight loads: MfmaUtil 13.7%, VALUBusy 17%).
__global__ __launch_bounds__(256, 3) void fused_tail_kernel(
    const unsigned short* __restrict__ attn,
    const unsigned short* __restrict__ Wot,
    const float* __restrict__ b_out,
    const unsigned short* __restrict__ srcres,
    const float* __restrict__ g1, const float* __restrict__ be1,
    const unsigned short* __restrict__ W1t,
    const unsigned short* __restrict__ W2t,
    const float* __restrict__ b1, const float* __restrict__ b2,
    const float* __restrict__ g2, const float* __restrict__ be2,
    float* __restrict__ out) {
  __shared__ unsigned short Ah[64 * 264];
  __shared__ unsigned short Hc[64 * 136];
  __shared__ float red[2][4][64];
  const int t = threadIdx.x;
  const int w = t >> 6, lane = t & 63;
  const int lr = lane & 15, lq = lane >> 4;
  const size_t rowbase = (size_t)blockIdx.x * 64;

  {
    const uint4* gsrc = (const uint4*)(attn + rowbase * 256);
#pragma unroll
    for (int u = 0; u < 8; u++) {
      const int idx = u * 256 + t;
      const int row = idx >> 5, c8 = idx & 31;
      *(uint4*)&Ah[row * 264 + c8 * 8] = gsrc[idx];
    }
  }
  __syncthreads();

  // ---- GEMM0: out-proj (K=256), depth-2 weight prefetch, full unroll
  f32x4 acc0[4][4] = {};
  {
    const size_t wb = (size_t)(w * 64 + lr) * 256 + lq * 8;
    bf16x8 wf0[2][4];
#pragma unroll
    for (int d = 0; d < 2; d++)
#pragma unroll
      for (int j = 0; j < 4; j++)
        wf0[d][j] = *(const bf16x8*)&Wot[wb + (size_t)j * 4096 + d * 32];
#pragma unroll
    for (int ks = 0; ks < 8; ks++) {
      bf16x8 c0 = wf0[ks & 1][0], c1 = wf0[ks & 1][1];
      bf16x8 c2 = wf0[ks & 1][2], c3 = wf0[ks & 1][3];
      if (ks + 2 < 8) {
#pragma unroll
        for (int j = 0; j < 4; j++)
          wf0[ks & 1][j] = *(const bf16x8*)&Wot[wb + (size_t)j * 4096 + (ks + 2) * 32];
      }
      bf16x8 af[4];
#pragma unroll
      for (int i = 0; i < 4; i++)
        af[i] = *(const bf16x8*)&Ah[(i * 16 + lr) * 264 + ks * 32 + lq * 8];
#pragma unroll
      for (int i = 0; i < 4; i++) {
        acc0[i][0] = __builtin_amdgcn_mfma_f32_16x16x32_bf16(af[i], c0, acc0[i][0], 0, 0, 0);
        acc0[i][1] = __builtin_amdgcn_mfma_f32_16x16x32_bf16(af[i], c1, acc0[i][1], 0, 0, 0);
        acc0[i][2] = __builtin_amdgcn_mfma_f32_16x16x32_bf16(af[i], c2, acc0[i][2], 0, 0, 0);
        acc0[i][3] = __builtin_amdgcn_mfma_f32_16x16x32_bf16(af[i], c3, acc0[i][3], 0, 0, 0);
      }
    }
  }
  // ---- epilogue0: +b_out +res(src) ; LN1 ; h -> Ah (bf16, in place)
  {
    float vsum[4][4], vsq[4][4];
#pragma unroll
    for (int i = 0; i < 4; i++)
#pragma unroll
      for (int r = 0; r < 4; r++) { vsum[i][r] = 0.f; vsq[i][r] = 0.f; }
#pragma unroll
    for (int j = 0; j < 4; j++) {
      const int col = w * 64 + j * 16 + lr;
      const float bv = b_out[col];
#pragma unroll
      for (int i = 0; i < 4; i++)
#pragma unroll
        for (int r = 0; r < 4; r++) {
          const int row = i * 16 + lq * 4 + r;
          float v = acc0[i][j][r] + bv + bf2f(srcres[(rowbase + row) * 256 + col]);
          acc0[i][j][r] = v;
          vsum[i][r] += v;
          vsq[i][r]  += v * v;
        }
    }
#pragma unroll
    for (int m = 1; m <= 8; m <<= 1)
#pragma unroll
      for (int i = 0; i < 4; i++)
#pragma unroll
        for (int r = 0; r < 4; r++) {
          vsum[i][r] += __shfl_xor(vsum[i][r], m, 64);
          vsq[i][r]  += __shfl_xor(vsq[i][r],  m, 64);
        }
    if (lr == 0) {
#pragma unroll
      for (int i = 0; i < 4; i++)
#pragma unroll
        for (int r = 0; r < 4; r++) {
          const int row = i * 16 + lq * 4 + r;
          red[0][w][row] = vsum[i][r];
          red[1][w][row] = vsq[i][r];
        }
    }
    __syncthreads();
    float mu[4][4], rstd[4][4];
#pragma unroll
    for (int i = 0; i < 4; i++)
#pragma unroll
      for (int r = 0; r < 4; r++) {
        const int row = i * 16 + lq * 4 + r;
        const float ts = red[0][0][row] + red[0][1][row] + red[0][2][row] + red[0][3][row];
        const float tq = red[1][0][row] + red[1][1][row] + red[1][2][row] + red[1][3][row];
        const float m_ = ts * (1.f / 256.f);
        mu[i][r] = m_;
        rstd[i][r] = rsqrtf(tq * (1.f / 256.f) - m_ * m_ + 1e-5f);
      }
#pragma unroll
    for (int j = 0; j < 4; j++) {
      const int col = w * 64 + j * 16 + lr;
      const float gg = g1[col], bb = be1[col];
#pragma unroll
      for (int i = 0; i < 4; i++)
#pragma unroll
        for (int r = 0; r < 4; r++) {
          const int row = i * 16 + lq * 4 + r;
          const float y = (acc0[i][j][r] - mu[i][r]) * rstd[i][r] * gg + bb;
          Ah[row * 264 + col] = f2bf(y);
        }
    }
  }
  __syncthreads();

  // ---- FFN: 8 chunks of 128 hidden cols; deep weight prefetch
  f32x4 acc2[4][4] = {};
  const int c1base = w * 32;
#pragma unroll 1
  for (int c2 = 0; c2 < 8; c2++) {
    f32x4 acc1[4][2] = {};
    const size_t w1r0 = (size_t)(c2 * 128 + c1base + lr) * 256 + lq * 8;
    const size_t w1r1 = w1r0 + (size_t)16 * 256;
    // GEMM1: depth-4 prefetch, full unroll
    bf16x8 wf[4][2];
#pragma unroll
    for (int d = 0; d < 4; d++) {
      wf[d][0] = *(const bf16x8*)&W1t[w1r0 + d * 32];
      wf[d][1] = *(const bf16x8*)&W1t[w1r1 + d * 32];
    }
#pragma unroll
    for (int ks = 0; ks < 8; ks++) {
      bf16x8 b0 = wf[ks & 3][0], b1v = wf[ks & 3][1];
      if (ks + 4 < 8) {
        wf[ks & 3][0] = *(const bf16x8*)&W1t[w1r0 + (ks + 4) * 32];
        wf[ks & 3][1] = *(const bf16x8*)&W1t[w1r1 + (ks + 4) * 32];
      }
      bf16x8 af[4];
#pragma unroll
      for (int i = 0; i < 4; i++)
        af[i] = *(const bf16x8*)&Ah[(i * 16 + lr) * 264 + ks * 32 + lq * 8];
#pragma unroll
      for (int i = 0; i < 4; i++) {
        acc1[i][0] = __builtin_amdgcn_mfma_f32_16x16x32_bf16(af[i], b0,  acc1[i][0], 0, 0, 0);
        acc1[i][1] = __builtin_amdgcn_mfma_f32_16x16x32_bf16(af[i], b1v, acc1[i][1], 0, 0, 0);
      }
    }
    __syncthreads();
#pragma unroll
    for (int j = 0; j < 2; j++) {
      const int colc = c1base + j * 16 + lr;
      const float bv = b1[c2 * 128 + colc];
#pragma unroll
      for (int i = 0; i < 4; i++)
#pragma unroll
        for (int r = 0; r < 4; r++)
          Hc[(i * 16 + lq * 4 + r) * 136 + colc] = f2bf(fmaxf(acc1[i][j][r] + bv, 0.f));
    }
    __syncthreads();
    // GEMM2: depth-2 prefetch, full unroll
    const size_t w2b = (size_t)(w * 64 + lr) * 1024 + c2 * 128 + lq * 8;
    bf16x8 wg[2][4];
#pragma unroll
    for (int d = 0; d < 2; d++)
#pragma unroll
      for (int j = 0; j < 4; j++)
        wg[d][j] = *(const bf16x8*)&W2t[w2b + (size_t)j * 16384 + d * 32];
#pragma unroll
    for (int ks = 0; ks < 4; ks++) {
      bf16x8 c0 = wg[ks & 1][0], c1 = wg[ks & 1][1];
      bf16x8 cc2 = wg[ks & 1][2], c3 = wg[ks & 1][3];
      if (ks + 2 < 4) {
#pragma unroll
        for (int j = 0; j < 4; j++)
          wg[ks & 1][j] = *(const bf16x8*)&W2t[w2b + (size_t)j * 16384 + (ks + 2) * 32];
      }
      bf16x8 af2[4];
#pragma unroll
      for (int i = 0; i < 4; i++)
        af2[i] = *(const bf16x8*)&Hc[(i * 16 + lr) * 136 + ks * 32 + lq * 8];
#pragma unroll
      for (int i = 0; i < 4; i++) {
        acc2[i][0] = __builtin_amdgcn_mfma_f32_16x16x32_bf16(af2[i], c0,  acc2[i][0], 0, 0, 0);
        acc2[i][1] = __builtin_amdgcn_mfma_f32_16x16x32_bf16(af2[i], c1,  acc2[i][1], 0, 0, 0);
        acc2[i][2] = __builtin_amdgcn_mfma_f32_16x16x32_bf16(af2[i], cc2, acc2[i][2], 0, 0, 0);
        acc2[i][3] = __builtin_amdgcn_mfma_f32_16x16x32_bf16(af2[i], c3,  acc2[i][3], 0, 0, 0);
      }
    }
  }
  // ---- epilogue2: +b2 +res(h from Ah) ; LN2 ; f32 out
  float vsum[4][4], vsq[4][4];
#pragma unroll
  for (int i = 0; i < 4; i++)
#pragma unroll
    for (int r = 0; r < 4; r++) { vsum[i][r] = 0.f; vsq[i][r] = 0.f; }
#pragma unroll
  for (int j = 0; j < 4; j++) {
    const int col = w * 64 + j * 16 + lr;
    const float bv = b2[col];
#pragma unroll
    for (int i = 0; i < 4; i++)
#pragma unroll
      for (int r = 0; r < 4; r++) {
        const int row = i * 16 + lq * 4 + r;
        float v = acc2[i][j][r] + bv + bf2f(Ah[row * 264 + col]);
        acc2[i][j][r] = v;
        vsum[i][r] += v;
        vsq[i][r]  += v * v;
      }
  }
#pragma unroll
  for (int m = 1; m <= 8; m <<= 1)
#pragma unroll
    for (int i = 0; i < 4; i++)
#pragma unroll
      for (int r = 0; r < 4; r++) {
        vsum[i][r] += __shfl_xor(vsum[i][r], m, 64);
        vsq[i][r]  += __shfl_xor(vsq[i][r],  m, 64);
      }
  __syncthreads();
  if (lr == 0) {
#pragma unroll
    for (int i = 0; i < 4; i++)
#pragma unroll
      for (int r = 0; r < 4; r++) {
        const int row = i * 16 + lq * 4 + r;
        red[0][w][row] = vsum[i][r];
        red[1][w][row] = vsq[i][r];
      }
  }
  __syncthreads();
  float mu[4][4], rstd[4][4];
#pragma unroll
  for (int i = 0; i < 4; i++)
#pragma unroll
    for (int r = 0; r < 4; r++) {
      const int row = i * 16 + lq * 4 + r;
      const float ts = red[0][0][row] + red[0][1][row] + red[0][2][row] + red[0][3][row];
      const float tq = red[1][0][row] + red[1][1][row] + red[1][2][row] + red[1][3][row];
      const float m_ = ts * (1.f / 256.f);
      mu[i][r] = m_;
      rstd[i][r] = rsqrtf(tq * (1.f / 256.f) - m_ * m_ + 1e-5f);
    }
#pragma unroll
  for (int j = 0; j < 4; j++) {
    const int col = w * 64 + j * 16 + lr;
    const float gg = g2[col], bb = be2[col];
#pragma unroll
    for (int i = 0; i < 4; i++)
#pragma unroll
      for (int r = 0; r < 4; r++) {
        const int row = i * 16 + lq * 4 + r;
        out[(rowbase + row) * 256 + col] = (acc2[i][j][r] - mu[i][r]) * rstd[i][r] * gg + bb;
      }
  }
}

// ---- bf16x8 (uint4) fused unpack + PACKED FMA (v_pk_fma_f32) into f32x2 acc
__device__ __forceinline__ void fma8(uint4 v, float w, f32x2* a) {
  const unsigned uu[4] = {v.x, v.y, v.z, v.w};
  const f32x2 w2 = {w, w};
#pragma unroll
  for (int i = 0; i < 4; i++) {
    union { unsigned u; float f; } lo, hi;
    lo.u = uu[i] << 16;
    hi.u = uu[i] & 0xffff0000u;
    f32x2 val = {lo.f, hi.f};
    a[i] += w2 * val;
  }
}

// ---- deformable attention: two-phase, int4 byte-offset tables (R0 structure)
__global__ __launch_bounds__(256) void deform_kernel(const unsigned short* __restrict__ valb,
                                                     const unsigned short* __restrict__ oab,
                                                     const float* __restrict__ refp,
                                                     unsigned short* __restrict__ outb) {
  __shared__ float4 sW[8][8][17];
  __shared__ int4   sI[8][8][17];
  const int t = threadIdx.x;
  const int bid = blockIdx.x;
  const int nb = (bid & 7) * 680 + (bid >> 3);
  const int tok0 = nb * 8;

  {
    const int g = t >> 5, h = (t >> 2) & 7, l = t & 3;
    const int tok = tok0 + g;
    const unsigned short* lg = oab + (size_t)tok * 384 + 256 + h * 16;
    uint4 lv0 = ((const uint4*)lg)[0];
    uint4 lv1 = ((const uint4*)lg)[1];
    const unsigned lw[8] = {lv0.x, lv0.y, lv0.z, lv0.w, lv1.x, lv1.y, lv1.z, lv1.w};
    float w[16];
#pragma unroll
    for (int i = 0; i < 8; i++) {
      union { unsigned u; float f; } lo, hi;
      lo.u = lw[i] << 16; hi.u = lw[i] & 0xffff0000u;
      w[2 * i] = lo.f; w[2 * i + 1] = hi.f;
    }
    float mx = -1e30f;
#pragma unroll
    for (int i = 0; i < 16; i++) mx = fmaxf(mx, w[i]);
    float s = 0.f;
#pragma unroll
    for (int i = 0; i < 16; i++) { w[i] = __expf(w[i] - mx); s += w[i]; }
    const float inv = 1.f / s;
    uint4 ov = *(const uint4*)(oab + (size_t)tok * 384 + h * 32 + l * 8);
    const unsigned owv[4] = {ov.x, ov.y, ov.z, ov.w};
    float off[8];
#pragma unroll
    for (int i = 0; i < 4; i++) {
      union { unsigned u; float f; } lo, hi;
      lo.u = owv[i] << 16; hi.u = owv[i] & 0xffff0000u;
      off[2 * i] = lo.f; off[2 * i + 1] = hi.f;
    }
    const float* rp = refp + (size_t)tok * 8 + l * 2;
    const int S = 128 >> l;
    const float Sf = (float)S;
    const float rx = rp[0] * Sf - 0.5f;
    const float ry = rp[1] * Sf - 0.5f;
#pragma unroll
    for (int p = 0; p < 4; p++) {
      const int idx = l * 4 + p;
      const float x = rx + off[p * 2 + 0];
      const float y = ry + off[p * 2 + 1];
      const float aw = w[idx] * inv;
      const float x0f = floorf(x), y0f = floorf(y);
      const int x0 = (int)x0f, y0 = (int)y0f;
      const float fx = x - x0f, fy = y - y0f;
      const bool xin0 = (x0 >= 0) & (x0 < S), xin1 = (x0 + 1 >= 0) & (x0 + 1 < S);
      const bool yin0 = (y0 >= 0) & (y0 < S), yin1 = (y0 + 1 >= 0) & (y0 + 1 < S);
      const int xc0 = min(max(x0, 0), S - 1), xc1 = min(max(x0 + 1, 0), S - 1);
      const int yc0 = min(max(y0, 0), S - 1), yc1 = min(max(y0 + 1, 0), S - 1);
      sW[g][h][idx] = make_float4(aw * (1.f - fx) * (1.f - fy) * (float)(xin0 & yin0),
                                  aw * fx * (1.f - fy)         * (float)(xin1 & yin0),
                                  aw * (1.f - fx) * fy         * (float)(xin0 & yin1),
                                  aw * fx * fy                 * (float)(xin1 & yin1));
      sI[g][h][idx] = make_int4((yc0 * S + xc0) << 9, (yc0 * S + xc1) << 9,
                                (yc1 * S + xc0) << 9, (yc1 * S + xc1) << 9);
    }
  }
  __syncthreads();

  const int g = t >> 5, h = (t >> 2) & 7, dc = t & 3;
  const int tok = tok0 + g;
  const int b = tok / LQN;
  f32x2 acc[4] = {};
  const int ST[4] = {0, 16384, 20480, 21504};
#pragma unroll
  for (int l = 0; l < 4; l++) {
    const char* vbc = (const char*)(valb + ((size_t)(b * LQN + ST[l])) * 256 + h * 32 + dc * 8);
#pragma unroll
    for (int p = 0; p < 4; p++) {
      float4 W4 = sW[g][h][l * 4 + p];
      int4   I4 = sI[g][h][l * 4 + p];
      uint4 v00 = *(const uint4*)(vbc + I4.x);
      uint4 v10 = *(const uint4*)(vbc + I4.y);
      uint4 v01 = *(const uint4*)(vbc + I4.z);
      uint4 v11 = *(const uint4*)(vbc + I4.w);
      fma8(v00, W4.x, acc);
      fma8(v10, W4.y, acc);
      fma8(v01, W4.z, acc);
      fma8(v11, W4.w, acc);
    }
  }
  unsigned o[4];
#pragma unroll
  for (int i = 0; i < 4; i++)
    o[i] = (unsigned)f2bf(acc[i].x) | ((unsigned)f2bf(acc[i].y) << 16);
  *(uint4*)(outb + (size_t)tok * 256 + h * 32 + dc * 8) = make_uint4(o[0], o[1], o[2], o[3]);
}

extern "C" void kernel_launch(void* const* d_in, const int* in_sizes, int n_in,
                              void* d_out, int out_size, void* d_ws, size_t ws_size,
                              hipStream_t stream) {
  (void)in_sizes; (void)n_in; (void)out_size; (void)ws_size;
  const float* src    = (const float*)d_in[0];
  const float* pos    = (const float*)d_in[1];
  const float* refp   = (const float*)d_in[2];
  const float* W_off  = (const float*)d_in[3];
  const float* b_off  = (const float*)d_in[4];
  const float* W_attn = (const float*)d_in[5];
  const float* b_attn = (const float*)d_in[6];
  const float* W_val  = (const float*)d_in[7];
  const float* b_val  = (const float*)d_in[8];
  const float* W_out  = (const float*)d_in[9];
  const float* b_out  = (const float*)d_in[10];
  const float* ln1_g  = (const float*)d_in[11];
  const float* ln1_b  = (const float*)d_in[12];
  const float* W1     = (const float*)d_in[13];
  const float* b1     = (const float*)d_in[14];
  const float* W2     = (const float*)d_in[15];
  const float* b2     = (const float*)d_in[16];
  const float* ln2_g  = (const float*)d_in[17];
  const float* ln2_b  = (const float*)d_in[18];

  char* ws = (char*)d_ws;
  unsigned short* Wt_val = (unsigned short*)ws;          // 65536
  unsigned short* Wt_oa  = Wt_val + 65536;               // 98304
  unsigned short* Wt_out = Wt_oa + 98304;                // 65536
  unsigned short* Wt_1   = Wt_out + 65536;               // 262144
  unsigned short* Wt_2   = Wt_1 + 262144;                // 262144
  float*          b_oa   = (float*)(Wt_2 + 262144);      // 384
  const size_t WPOOL = 2u * 1024 * 1024;

  const size_t SZ_bf = (size_t)TOKS * 256 * 2;           // 22.3 MB
  const size_t SZ_oa = (size_t)TOKS * 384 * 2;           // 33.4 MB

  unsigned short* srcb = (unsigned short*)(ws + WPOOL);
  unsigned short* qb   = (unsigned short*)(ws + WPOOL + SZ_bf);
  unsigned short* valb = (unsigned short*)(ws + WPOOL + 2 * SZ_bf);
  unsigned short* oab  = (unsigned short*)(ws + WPOOL + 3 * SZ_bf);
  // alias (lifetime-disjoint):
  unsigned short* attnoutb = qb;     // deform out; qb dead after proj

  // 1. prep + LDS-tiled weight transposes + bias concat
  prewt_kernel<<<11617, 256, 0, stream>>>(src, pos, srcb, qb,
                                          W_val, W_off, W_attn, W_out, W1, W2, b_off, b_attn,
                                          Wt_val, Wt_oa, Wt_out, Wt_1, Wt_2, b_oa);

  // 2. merged projections: value (N=256) + off/attn (N=384)
  proj_kernel<<<dim3(340, 5), 256, 0, stream>>>(srcb, qb, Wt_val, Wt_oa, b_val, b_oa,
                                                valb, oab);

  // 3. deformable attention (8 tokens/block, XCD-swizzled)
  deform_kernel<<<TOKS / 8, 256, 0, stream>>>(valb, oab, refp, attnoutb);

  // 4. fused tail: out-proj + res(src) + LN1 + FFN + res(h) + LN2 -> d_out (f32)
  fused_tail_kernel<<<680, 256, 0, stream>>>(attnoutb, Wt_out, b_out, srcb, ln1_g, ln1_b,
                                             Wt_1, Wt_2, b1, b2, ln2_g, ln2_b,
                                             (float*)d_out);
}